// Round 6
// baseline (643.659 us; speedup 1.0000x reference)
//
#include <hip/hip_runtime.h>
#include <hip/hip_bf16.h>

typedef __attribute__((ext_vector_type(8))) short short8;
typedef __attribute__((ext_vector_type(4))) float f32x4;
typedef __attribute__((ext_vector_type(2))) float f32x2;

__device__ inline unsigned short f2bf(float f) {
    union { float f; unsigned int u; } x; x.f = f;
    return (unsigned short)((x.u + 0x7fffu + ((x.u >> 16) & 1u)) >> 16);
}

// async global->LDS, 16B per lane. LDS dest must be wave-uniform base + lane*16.
#define ASYNC16(gptr, lptr)                                                      \
    __builtin_amdgcn_global_load_lds(                                            \
        (const __attribute__((address_space(1))) unsigned int*)(gptr),           \
        (__attribute__((address_space(3))) unsigned int*)(lptr), 16, 0, 0)

// feature permutation (per 64-block): stored position p holds original feature sg(p)
__device__ __host__ inline int sg(int j) {
    int p = j & 63;
    return (j & ~63) | ((p >> 2) + 16 * (p & 3));
}

// ---- Slice-major layouts (4 slices of 64 stored-features each) ----
// fp8 support:  sup[s][node][64]  bytes   (slice stride N*64 B)
// bf16 h / xb:  h[s][node][64]    ushorts (slice stride N*64 ushorts = 128 B rows)
// K-step 32 of the GEMM always lies inside one slice; addressing-only change.

// rp[n] = lower_bound(dst, n) via boundary diff (dst sorted). One streamed pass.
__global__ void rowptr_kernel(const int* __restrict__ dst, int* __restrict__ rp,
                              int E, int N) {
    int e = blockIdx.x * blockDim.x + threadIdx.x;
    if (e >= E) return;
    int d1 = dst[e];
    int d0 = (e == 0) ? -1 : dst[e - 1];
    for (int n = d0 + 1; n <= d1; n++) rp[n] = e;
    if (e <= N) {                      // tail: nodes past the last dst value
        int dlast = dst[E - 1];
        if (e > dlast) rp[e] = E;
    }
}

// pack (src:17b | bf16 weight sans sign:15b) into one u32, 4 edges/thread.
// weights >= 0 so the sign bit is free; bf16 rel err 2^-9 << fp8 row quant.
__global__ void epack_kernel(const int* __restrict__ src, const float* __restrict__ w,
                             unsigned int* __restrict__ ep, int E4) {
    int i = blockIdx.x * blockDim.x + threadIdx.x;
    if (i >= E4) return;
    const int4 sv = ((const int4*)src)[i];
    const float4 wv = ((const float4*)w)[i];
    uint4 o;
    o.x = ((unsigned int)(f2bf(wv.x) & 0x7fffu) << 17) | (unsigned int)sv.x;
    o.y = ((unsigned int)(f2bf(wv.y) & 0x7fffu) << 17) | (unsigned int)sv.y;
    o.z = ((unsigned int)(f2bf(wv.z) & 0x7fffu) << 17) | (unsigned int)sv.z;
    o.w = ((unsigned int)(f2bf(wv.w) & 0x7fffu) << 17) | (unsigned int)sv.w;
    ((uint4*)ep)[i] = o;
}

__device__ inline float unpackw(unsigned int p) {
    return __uint_as_float((p >> 17) << 16);   // bf16 sans sign -> f32
}

// x fp32 -> bf16 (round-half-up), 8 elements/thread, SLICE-MAJOR output.
__global__ void x2bf_kernel(const float* __restrict__ x, unsigned short* __restrict__ xb,
                            int n8, int N) {
    int i = blockIdx.x * blockDim.x + threadIdx.x;
    if (i >= n8) return;
    const int n  = i >> 5;             // node
    const int f0 = (i & 31) * 8;       // feature start (0..248)
    const uint4* p = (const uint4*)(x + (size_t)n * 256 + f0);
    uint4 u = p[0], v = p[1];
    uint4 pk;
    pk.x = ((u.x + 0x8000u) >> 16) | ((u.y + 0x8000u) & 0xffff0000u);
    pk.y = ((u.z + 0x8000u) >> 16) | ((u.w + 0x8000u) & 0xffff0000u);
    pk.z = ((v.x + 0x8000u) >> 16) | ((v.y + 0x8000u) & 0xffff0000u);
    pk.w = ((v.z + 0x8000u) >> 16) | ((v.w + 0x8000u) & 0xffff0000u);
    *(uint4*)(xb + (size_t)(f0 >> 6) * ((size_t)N * 64) + (size_t)n * 64 + (f0 & 63)) = pk;
}

// Weight/bias prep. blocks 0..255 -> W1t (k not permuted), 256..511 -> W2t (k sg-permuted),
// 512..639 -> WLt (k sg-permuted), 640 -> b1p, 641 -> b2p (sg-permuted biases).
__global__ void prep_kernel(const float* __restrict__ W1, const float* __restrict__ W2,
                            const float* __restrict__ WL1, const float* __restrict__ WL2,
                            const float* __restrict__ b1, const float* __restrict__ b2,
                            unsigned short* __restrict__ W1t, unsigned short* __restrict__ W2t,
                            unsigned short* __restrict__ WLt,
                            float* __restrict__ b1p, float* __restrict__ b2p) {
    int b = blockIdx.x, k = threadIdx.x;
    if (b < 256) {
        W1t[(size_t)b * 256 + k] = f2bf(W1[(size_t)k * 256 + b]);
    } else if (b < 512) {
        int n = b - 256;
        W2t[(size_t)n * 256 + k] = f2bf(W2[(size_t)sg(k) * 256 + n]);
    } else if (b < 640) {
        int c = b - 512;
        int ks = sg(k);
        float v = (c < 64) ? WL1[(size_t)ks * 64 + c] : WL2[(size_t)ks * 64 + (c - 64)];
        WLt[(size_t)c * 256 + k] = f2bf(v);
    } else if (b == 640) {
        b1p[k] = b1[sg(k)];
    } else {
        b2p[k] = b2[sg(k)];
    }
}

// C fp8 = A @ Bt^T. A is SLICE-MAJOR bf16 [4][M][64]; C written SLICE-MAJOR fp8
// [4][M][64] with output cols sg-permuted per 64-block. m97-style staging.
__global__ __launch_bounds__(256) void gemm_f8_kernel(
    const unsigned short* __restrict__ A, const unsigned short* __restrict__ Bt,
    unsigned char* __restrict__ C, int M)
{
    __shared__ __align__(16) unsigned short As[128 * 32];
    __shared__ __align__(16) unsigned short Bs[128 * 32];
    const int t = threadIdx.x;
    const int row0 = blockIdx.y * 128;
    const int col0 = blockIdx.x * 128;
    const int wid = t >> 6, lane = t & 63;
    const int wm = (wid >> 1) * 64, wn = (wid & 1) * 64;
    const int qk = (lane >> 4) * 8, r16 = lane & 15;

    const size_t Asl = (size_t)M * 64;   // A slice stride (ushorts)
    const int c0 = t, c1 = t + 256;
    const int am0 = min(row0 + (c0 >> 2), M - 1);
    const int am1 = min(row0 + (c1 >> 2), M - 1);
    const int ak0 = (c0 & 3) * 8, ak1 = (c1 & 3) * 8;
    const int bm0 = col0 + (c0 >> 2), bm1 = col0 + (c1 >> 2);

    f32x4 acc[4][4];
#pragma unroll
    for (int i = 0; i < 4; i++)
#pragma unroll
        for (int j = 0; j < 4; j++) acc[i][j] = (f32x4){0.f, 0.f, 0.f, 0.f};

    for (int k0 = 0; k0 < 256; k0 += 32) {
        const size_t sb = (size_t)(k0 >> 6) * Asl + (k0 & 63);
        ASYNC16(A + sb + (size_t)am0 * 64 + ak0, &As[c0 * 8]);
        ASYNC16(A + sb + (size_t)am1 * 64 + ak1, &As[c1 * 8]);
        ASYNC16(Bt + (size_t)bm0 * 256 + k0 + ak0, &Bs[c0 * 8]);
        ASYNC16(Bt + (size_t)bm1 * 256 + k0 + ak1, &Bs[c1 * 8]);
        __syncthreads();
        short8 av[4], bv[4];
#pragma unroll
        for (int mt = 0; mt < 4; mt++) av[mt] = *(const short8*)(&As[(wm + mt * 16 + r16) * 32 + qk]);
#pragma unroll
        for (int nt = 0; nt < 4; nt++) bv[nt] = *(const short8*)(&Bs[(wn + nt * 16 + r16) * 32 + qk]);
#pragma unroll
        for (int mt = 0; mt < 4; mt++)
#pragma unroll
            for (int nt = 0; nt < 4; nt++)
                acc[mt][nt] = __builtin_amdgcn_mfma_f32_16x16x32_bf16(av[mt], bv[nt], acc[mt][nt], 0, 0, 0);
        __syncthreads();
    }
    // permuted fp8 epilogue, slice-major store:
    // stored col = col0 + wn + r16*4 + {0..3}  == sg-permutation of orig cols
    const int scol = col0 + wn + r16 * 4;
    unsigned char* cb = C + (size_t)(scol >> 6) * ((size_t)M * 64) + (scol & 63);
#pragma unroll
    for (int mt = 0; mt < 4; mt++) {
        const int rowb = row0 + wm + mt * 16 + (lane >> 4) * 4;
#pragma unroll
        for (int r = 0; r < 4; r++) {
            const int row = rowb + r;
            if (row >= M) continue;
            int w = 0;
            w = __builtin_amdgcn_cvt_pk_fp8_f32(acc[mt][0][r], acc[mt][1][r], w, false);
            w = __builtin_amdgcn_cvt_pk_fp8_f32(acc[mt][2][r], acc[mt][3][r], w, true);
            *(unsigned int*)(cb + (size_t)row * 64) = (unsigned int)w;
        }
    }
}

// logits = h2 @ WLt^T + bias. A (h2) is SLICE-MAJOR bf16 [4][M][64].
__global__ __launch_bounds__(256) void head_kernel(
    const unsigned short* __restrict__ A, const unsigned short* __restrict__ Bt,
    const float* __restrict__ bL1, const float* __restrict__ bL2,
    float* __restrict__ out, int M)
{
    __shared__ __align__(16) unsigned short As[128 * 32];
    __shared__ __align__(16) unsigned short Bs[128 * 32];
    const int t = threadIdx.x;
    const int row0 = blockIdx.x * 128;
    const int wid = t >> 6, lane = t & 63;
    const int wm = (wid >> 1) * 64, wn = (wid & 1) * 64;
    const int qk = (lane >> 4) * 8, r16 = lane & 15;

    const size_t Asl = (size_t)M * 64;
    const int c0 = t, c1 = t + 256;
    const int am0 = min(row0 + (c0 >> 2), M - 1);
    const int am1 = min(row0 + (c1 >> 2), M - 1);
    const int ak0 = (c0 & 3) * 8, ak1 = (c1 & 3) * 8;
    const int bm0 = c0 >> 2, bm1 = c1 >> 2;          // B has exactly 128 rows

    f32x4 acc[4][4];
#pragma unroll
    for (int i = 0; i < 4; i++)
#pragma unroll
        for (int j = 0; j < 4; j++) acc[i][j] = (f32x4){0.f, 0.f, 0.f, 0.f};

    for (int k0 = 0; k0 < 256; k0 += 32) {
        const size_t sb = (size_t)(k0 >> 6) * Asl + (k0 & 63);
        ASYNC16(A + sb + (size_t)am0 * 64 + ak0, &As[c0 * 8]);
        ASYNC16(A + sb + (size_t)am1 * 64 + ak1, &As[c1 * 8]);
        ASYNC16(Bt + (size_t)bm0 * 256 + k0 + ak0, &Bs[c0 * 8]);
        ASYNC16(Bt + (size_t)bm1 * 256 + k0 + ak1, &Bs[c1 * 8]);
        __syncthreads();
        short8 av[4], bv[4];
#pragma unroll
        for (int mt = 0; mt < 4; mt++) av[mt] = *(const short8*)(&As[(wm + mt * 16 + r16) * 32 + qk]);
#pragma unroll
        for (int nt = 0; nt < 4; nt++) bv[nt] = *(const short8*)(&Bs[(wn + nt * 16 + r16) * 32 + qk]);
#pragma unroll
        for (int mt = 0; mt < 4; mt++)
#pragma unroll
            for (int nt = 0; nt < 4; nt++)
                acc[mt][nt] = __builtin_amdgcn_mfma_f32_16x16x32_bf16(av[mt], bv[nt], acc[mt][nt], 0, 0, 0);
        __syncthreads();
    }
#pragma unroll
    for (int mt = 0; mt < 4; mt++) {
#pragma unroll
        for (int r = 0; r < 4; r++) {
            int row = row0 + wm + mt * 16 + (lane >> 4) * 4 + r;
            if (row >= M) continue;
#pragma unroll
            for (int nt = 0; nt < 4; nt++) {
                int col = wn + nt * 16 + r16;
                float v = acc[mt][nt][r];
                if (col < 64) {
                    out[(size_t)row * 64 + col] = v + bL1[col];
                } else {
                    out[(size_t)M * 64 + (size_t)row * 64 + (col - 64)] = v + bL2[col - 64];
                }
            }
        }
    }
}

// decode 16 fp8 (uint4) and FMA into a[16]
__device__ inline void acc16f8(float* a, uint4 r, float w) {
    f32x2 p;
    p = __builtin_amdgcn_cvt_pk_f32_fp8((int)r.x, false); a[0]  += w * p.x; a[1]  += w * p.y;
    p = __builtin_amdgcn_cvt_pk_f32_fp8((int)r.x, true);  a[2]  += w * p.x; a[3]  += w * p.y;
    p = __builtin_amdgcn_cvt_pk_f32_fp8((int)r.y, false); a[4]  += w * p.x; a[5]  += w * p.y;
    p = __builtin_amdgcn_cvt_pk_f32_fp8((int)r.y, true);  a[6]  += w * p.x; a[7]  += w * p.y;
    p = __builtin_amdgcn_cvt_pk_f32_fp8((int)r.z, false); a[8]  += w * p.x; a[9]  += w * p.y;
    p = __builtin_amdgcn_cvt_pk_f32_fp8((int)r.z, true);  a[10] += w * p.x; a[11] += w * p.y;
    p = __builtin_amdgcn_cvt_pk_f32_fp8((int)r.w, false); a[12] += w * p.x; a[13] += w * p.y;
    p = __builtin_amdgcn_cvt_pk_f32_fp8((int)r.w, true);  a[14] += w * p.x; a[15] += w * p.y;
}

// Feature-sliced SPMM, 4 slices x 64B. slice = blockIdx.x & 3; with %8 round-robin
// block->XCD dispatch each XCD serves ONE slice (pinned to XCD pair {s, s+4}):
// per-XCD gather working set = N*64B = 6.4MB (vs 25.6MB unsliced).
// Wave layout: 8 nodes x 2 edge-slots x 4 lanes x 16B. Depth-2 pipelined gathers
// (R5 structure). Reduction = one shfl_xor(4). Writes 128B/node contiguous.
template <bool PACKED>
__global__ __launch_bounds__(256) void spmm_slice_kernel(
    const unsigned char* __restrict__ sup, const int* __restrict__ rp,
    const unsigned int* __restrict__ ep, const int* __restrict__ esrc,
    const float* __restrict__ ew, const float* __restrict__ bias,
    unsigned short* __restrict__ out, int nnodes, int E)
{
    const int s    = blockIdx.x & 3;
    const int nb   = blockIdx.x >> 2;
    const int lane = threadIdx.x & 63;
    const int wid  = threadIdx.x >> 6;
    const int nsub = lane >> 3;          // 0..7
    const int slot = (lane >> 2) & 1;    // 0..1
    const int fl   = lane & 3;           // 16B quarter of the 64B slice
    const int node = nb * 32 + wid * 8 + nsub;
    const int nc   = node < nnodes ? node : nnodes - 1;
    const int beg  = rp[nc], end = rp[nc + 1];
    const int cnt  = (end - beg - slot + 1) >> 1;   // this slot's edge count (>=0)

    int cmax = cnt;                      // wave-max trip count (uniform loop)
#pragma unroll
    for (int d = 1; d < 64; d <<= 1) { int o = __shfl_xor(cmax, d); cmax = o > cmax ? o : cmax; }

    const unsigned char* sups = sup + (size_t)s * ((size_t)nnodes * 64) + fl * 16;
    const int Emax = E - 1;

    float a[16];
#pragma unroll
    for (int i = 0; i < 16; i++) a[i] = 0.f;

    if (cmax > 0) {
        int e2 = beg + slot;
        unsigned int p0 = 0, p1 = 0; int s0 = 0, s1 = 0; float w0f = 0.f, w1f = 0.f;
        if (PACKED) {
            p0 = ep[min(e2, Emax)];
            p1 = ep[min(e2 + 2, Emax)];
        } else {
            s0 = esrc[min(e2, Emax)];     w0f = ew[min(e2, Emax)];
            s1 = esrc[min(e2 + 2, Emax)]; w1f = ew[min(e2 + 2, Emax)];
        }
        uint4 r0 = PACKED ? *(const uint4*)(sups + (size_t)(p0 & 0x1ffffu) * 64)
                          : *(const uint4*)(sups + (size_t)s0 * 64);
        for (int k = 0; k < cmax; ++k) {
            uint4 r1;
            float w;
            if (PACKED) {
                r1 = *(const uint4*)(sups + (size_t)(p1 & 0x1ffffu) * 64);  // in flight
                const unsigned int p2 = ep[min(e2 + 4, Emax)];              // in flight
                w = (k < cnt) ? unpackw(p0) : 0.f;
                p0 = p1; p1 = p2;
            } else {
                r1 = *(const uint4*)(sups + (size_t)s1 * 64);
                const int s2   = esrc[min(e2 + 4, Emax)];
                const float wf = ew[min(e2 + 4, Emax)];
                w = (k < cnt) ? w0f : 0.f;
                s0 = s1; w0f = w1f; s1 = s2; w1f = wf;
            }
            acc16f8(a, r0, w);
            r0 = r1;
            e2 += 2;
        }
    }

    // combine the two edge slots (lane^4 flips slot, same node/fl)
#pragma unroll
    for (int i = 0; i < 16; i++) a[i] += __shfl_xor(a[i], 4);

    if (slot == 0 && node < nnodes) {
        const int fb = s * 64 + fl * 16;
        const float4 b0 = *(const float4*)(bias + fb);
        const float4 b1 = *(const float4*)(bias + fb + 4);
        const float4 b2 = *(const float4*)(bias + fb + 8);
        const float4 b3 = *(const float4*)(bias + fb + 12);
        a[0] += b0.x; a[1] += b0.y; a[2]  += b0.z; a[3]  += b0.w;
        a[4] += b1.x; a[5] += b1.y; a[6]  += b1.z; a[7]  += b1.w;
        a[8] += b2.x; a[9] += b2.y; a[10] += b2.z; a[11] += b2.w;
        a[12] += b3.x; a[13] += b3.y; a[14] += b3.z; a[15] += b3.w;
#pragma unroll
        for (int i = 0; i < 16; i++) a[i] = a[i] > 0.f ? a[i] : 0.f;
        uint4 o0, o1;
        o0.x = (unsigned int)f2bf(a[0])  | ((unsigned int)f2bf(a[1])  << 16);
        o0.y = (unsigned int)f2bf(a[2])  | ((unsigned int)f2bf(a[3])  << 16);
        o0.z = (unsigned int)f2bf(a[4])  | ((unsigned int)f2bf(a[5])  << 16);
        o0.w = (unsigned int)f2bf(a[6])  | ((unsigned int)f2bf(a[7])  << 16);
        o1.x = (unsigned int)f2bf(a[8])  | ((unsigned int)f2bf(a[9])  << 16);
        o1.y = (unsigned int)f2bf(a[10]) | ((unsigned int)f2bf(a[11]) << 16);
        o1.z = (unsigned int)f2bf(a[12]) | ((unsigned int)f2bf(a[13]) << 16);
        o1.w = (unsigned int)f2bf(a[14]) | ((unsigned int)f2bf(a[15]) << 16);
        unsigned short* op = out + (size_t)s * ((size_t)nnodes * 64) + (size_t)node * 64 + fl * 16;
        *(uint4*)op = o0;
        *(uint4*)(op + 8) = o1;
    }
}

extern "C" void kernel_launch(void* const* d_in, const int* in_sizes, int n_in,
                              void* d_out, int out_size, void* d_ws, size_t ws_size,
                              hipStream_t stream) {
    const float* x    = (const float*)d_in[0];
    const int*   esrc = (const int*)d_in[1];
    const int*   edst = (const int*)d_in[2];
    const float* ew   = (const float*)d_in[3];
    const float* W1   = (const float*)d_in[4];
    const float* b1   = (const float*)d_in[5];
    const float* W2   = (const float*)d_in[6];
    const float* b2   = (const float*)d_in[7];
    const float* WL1  = (const float*)d_in[8];
    const float* bL1  = (const float*)d_in[9];
    const float* WL2  = (const float*)d_in[10];
    const float* bL2  = (const float*)d_in[11];
    float* out = (float*)d_out;

    const int N = in_sizes[0] / 256;   // 100000
    const int E = in_sizes[1];         // 3200000

    char* ws = (char*)d_ws;
    size_t off = 0;
    auto alloc = [&](size_t bytes) -> void* {
        void* p = ws + off;
        off = (off + bytes + 511) & ~(size_t)511;   // 512B-align: rows stay line-aligned
        return p;
    };
    int* rp              = (int*)alloc((size_t)(N + 1) * 4);
    unsigned short* W1t  = (unsigned short*)alloc((size_t)256 * 256 * 2);
    unsigned short* W2t  = (unsigned short*)alloc((size_t)256 * 256 * 2);
    unsigned short* WLt  = (unsigned short*)alloc((size_t)128 * 256 * 2);
    float* b1p           = (float*)alloc(256 * 4);
    float* b2p           = (float*)alloc(256 * 4);
    unsigned char* sup8  = (unsigned char*)alloc((size_t)N * 256);      // fp8 support, slice-major
    unsigned short* hbuf = (unsigned short*)alloc((size_t)N * 256 * 2); // xb, then h1/h2 (aliased)
    unsigned int* ep     = (unsigned int*)alloc((size_t)E * 4);         // packed edges (LAST alloc)
    const bool packed = (off <= ws_size);   // ws overflow guard: fall back to raw esrc/ew

    const int mblocks = (N + 127) / 128;
    const int sblocks = 4 * ((N + 31) / 32);

    rowptr_kernel<<<(E + 255) / 256, 256, 0, stream>>>(edst, rp, E, N);
    if (packed)
        epack_kernel<<<(E / 4 + 255) / 256, 256, 0, stream>>>(esrc, ew, ep, E / 4);
    x2bf_kernel<<<(N * 256 / 8 + 255) / 256, 256, 0, stream>>>(x, hbuf, N * 256 / 8, N);
    prep_kernel<<<642, 256, 0, stream>>>(W1, W2, WL1, WL2, b1, b2, W1t, W2t, WLt, b1p, b2p);

    // layer 1: support fp8 e4m3 (sg-permuted cols, slice-major)
    gemm_f8_kernel<<<dim3(2, mblocks), 256, 0, stream>>>(hbuf, W1t, sup8, N);
    if (packed)
        spmm_slice_kernel<true><<<sblocks, 256, 0, stream>>>(sup8, rp, ep, esrc, ew, b1p, hbuf, N, E);
    else
        spmm_slice_kernel<false><<<sblocks, 256, 0, stream>>>(sup8, rp, ep, esrc, ew, b1p, hbuf, N, E);
    // layer 2 (W2t k-rows pre-permuted to consume sg order; output sg-permuted again)
    gemm_f8_kernel<<<dim3(2, mblocks), 256, 0, stream>>>(hbuf, W2t, sup8, N);
    if (packed)
        spmm_slice_kernel<true><<<sblocks, 256, 0, stream>>>(sup8, rp, ep, esrc, ew, b2p, hbuf, N, E);
    else
        spmm_slice_kernel<false><<<sblocks, 256, 0, stream>>>(sup8, rp, ep, esrc, ew, b2p, hbuf, N, E);
    head_kernel<<<mblocks, 256, 0, stream>>>(hbuf, WLt, bL1, bL2, out, N);
}

// Round 7
// 526.463 us; speedup vs baseline: 1.2226x; 1.2226x over previous
//
#include <hip/hip_runtime.h>
#include <hip/hip_bf16.h>

typedef __attribute__((ext_vector_type(8))) short short8;
typedef __attribute__((ext_vector_type(4))) float f32x4;
typedef __attribute__((ext_vector_type(2))) float f32x2;

__device__ inline unsigned short f2bf(float f) {
    union { float f; unsigned int u; } x; x.f = f;
    return (unsigned short)((x.u + 0x7fffu + ((x.u >> 16) & 1u)) >> 16);
}

// async global->LDS, 16B per lane. LDS dest must be wave-uniform base + lane*16.
#define ASYNC16(gptr, lptr)                                                      \
    __builtin_amdgcn_global_load_lds(                                            \
        (const __attribute__((address_space(1))) unsigned int*)(gptr),           \
        (__attribute__((address_space(3))) unsigned int*)(lptr), 16, 0, 0)

// feature permutation (per 64-block): stored position p holds original feature sg(p)
__device__ __host__ inline int sg(int j) {
    int p = j & 63;
    return (j & ~63) | ((p >> 2) + 16 * (p & 3));
}

// rp[n] = lower_bound(dst, n) via boundary diff (dst sorted). One streamed pass.
__global__ void rowptr_kernel(const int* __restrict__ dst, int* __restrict__ rp,
                              int E, int N) {
    int e = blockIdx.x * blockDim.x + threadIdx.x;
    if (e >= E) return;
    int d1 = dst[e];
    int d0 = (e == 0) ? -1 : dst[e - 1];
    for (int n = d0 + 1; n <= d1; n++) rp[n] = e;
    if (e <= N) {                      // tail: nodes past the last dst value
        int dlast = dst[E - 1];
        if (e > dlast) rp[e] = E;
    }
}

// x fp32 -> bf16 (round-half-up), 8 elements/thread
__global__ void x2bf_kernel(const float* __restrict__ x, unsigned short* __restrict__ xb,
                            int n8) {
    int i = blockIdx.x * blockDim.x + threadIdx.x;
    if (i >= n8) return;
    const uint4* p = (const uint4*)(x + (size_t)i * 8);
    uint4 u = p[0], v = p[1];
    uint4 pk;
    pk.x = ((u.x + 0x8000u) >> 16) | ((u.y + 0x8000u) & 0xffff0000u);
    pk.y = ((u.z + 0x8000u) >> 16) | ((u.w + 0x8000u) & 0xffff0000u);
    pk.z = ((v.x + 0x8000u) >> 16) | ((v.y + 0x8000u) & 0xffff0000u);
    pk.w = ((v.z + 0x8000u) >> 16) | ((v.w + 0x8000u) & 0xffff0000u);
    *(uint4*)(xb + (size_t)i * 8) = pk;
}

// Weight/bias prep. blocks 0..255 -> W1t (k not permuted), 256..511 -> W2t (k sg-permuted),
// 512..639 -> WLt (k sg-permuted), 640 -> b1p, 641 -> b2p (sg-permuted biases).
__global__ void prep_kernel(const float* __restrict__ W1, const float* __restrict__ W2,
                            const float* __restrict__ WL1, const float* __restrict__ WL2,
                            const float* __restrict__ b1, const float* __restrict__ b2,
                            unsigned short* __restrict__ W1t, unsigned short* __restrict__ W2t,
                            unsigned short* __restrict__ WLt,
                            float* __restrict__ b1p, float* __restrict__ b2p) {
    int b = blockIdx.x, k = threadIdx.x;
    if (b < 256) {
        W1t[(size_t)b * 256 + k] = f2bf(W1[(size_t)k * 256 + b]);
    } else if (b < 512) {
        int n = b - 256;
        W2t[(size_t)n * 256 + k] = f2bf(W2[(size_t)sg(k) * 256 + n]);
    } else if (b < 640) {
        int c = b - 512;
        int ks = sg(k);
        float v = (c < 64) ? WL1[(size_t)ks * 64 + c] : WL2[(size_t)ks * 64 + (c - 64)];
        WLt[(size_t)c * 256 + k] = f2bf(v);
    } else if (b == 640) {
        b1p[k] = b1[sg(k)];
    } else {
        b2p[k] = b2[sg(k)];
    }
}

// C8[M][256] fp8 = A[M][256](bf16) @ Bt^T, output columns sg-permuted per 64-block.
// m97-style: global_load_lds staging (16B/lane), unpadded LDS [128][32].
__global__ __launch_bounds__(256) void gemm_f8_kernel(
    const unsigned short* __restrict__ A, const unsigned short* __restrict__ Bt,
    unsigned char* __restrict__ C, int M)
{
    __shared__ __align__(16) unsigned short As[128 * 32];
    __shared__ __align__(16) unsigned short Bs[128 * 32];
    const int t = threadIdx.x;
    const int row0 = blockIdx.y * 128;
    const int col0 = blockIdx.x * 128;
    const int wid = t >> 6, lane = t & 63;
    const int wm = (wid >> 1) * 64, wn = (wid & 1) * 64;
    const int qk = (lane >> 4) * 8, r16 = lane & 15;

    // staging chunks: c covers (m = c>>2, ko = (c&3)*8); LDS offset = c*16B (lane-contiguous)
    const int c0 = t, c1 = t + 256;
    const int am0 = min(row0 + (c0 >> 2), M - 1);
    const int am1 = min(row0 + (c1 >> 2), M - 1);
    const int ak0 = (c0 & 3) * 8, ak1 = (c1 & 3) * 8;
    const int bm0 = col0 + (c0 >> 2), bm1 = col0 + (c1 >> 2);

    f32x4 acc[4][4];
#pragma unroll
    for (int i = 0; i < 4; i++)
#pragma unroll
        for (int j = 0; j < 4; j++) acc[i][j] = (f32x4){0.f, 0.f, 0.f, 0.f};

    for (int k0 = 0; k0 < 256; k0 += 32) {
        ASYNC16(A + (size_t)am0 * 256 + k0 + ak0, &As[c0 * 8]);
        ASYNC16(A + (size_t)am1 * 256 + k0 + ak1, &As[c1 * 8]);
        ASYNC16(Bt + (size_t)bm0 * 256 + k0 + ak0, &Bs[c0 * 8]);
        ASYNC16(Bt + (size_t)bm1 * 256 + k0 + ak1, &Bs[c1 * 8]);
        __syncthreads();
        short8 av[4], bv[4];
#pragma unroll
        for (int mt = 0; mt < 4; mt++) av[mt] = *(const short8*)(&As[(wm + mt * 16 + r16) * 32 + qk]);
#pragma unroll
        for (int nt = 0; nt < 4; nt++) bv[nt] = *(const short8*)(&Bs[(wn + nt * 16 + r16) * 32 + qk]);
#pragma unroll
        for (int mt = 0; mt < 4; mt++)
#pragma unroll
            for (int nt = 0; nt < 4; nt++)
                acc[mt][nt] = __builtin_amdgcn_mfma_f32_16x16x32_bf16(av[mt], bv[nt], acc[mt][nt], 0, 0, 0);
        __syncthreads();
    }
    // permuted fp8 epilogue: lane packs its 4 cols of one row into one dword.
    // stored[col0 + wn + r16*4 + nt] = fp8(orig col0 + wn + nt*16 + r16)  == sg-permutation
#pragma unroll
    for (int mt = 0; mt < 4; mt++) {
        const int rowb = row0 + wm + mt * 16 + (lane >> 4) * 4;
#pragma unroll
        for (int r = 0; r < 4; r++) {
            const int row = rowb + r;
            if (row >= M) continue;
            int w = 0;
            w = __builtin_amdgcn_cvt_pk_fp8_f32(acc[mt][0][r], acc[mt][1][r], w, false);
            w = __builtin_amdgcn_cvt_pk_fp8_f32(acc[mt][2][r], acc[mt][3][r], w, true);
            *(unsigned int*)(C + (size_t)row * 256 + col0 + wn + r16 * 4) = (unsigned int)w;
        }
    }
}

// logits = h2 @ WLt^T + bias (WLt k-dim pre-permuted to match h2's sg order).
// cols 0..63 -> out0, 64..127 -> out1 (concatenated). Same m97 staging.
__global__ __launch_bounds__(256) void head_kernel(
    const unsigned short* __restrict__ A, const unsigned short* __restrict__ Bt,
    const float* __restrict__ bL1, const float* __restrict__ bL2,
    float* __restrict__ out, int M)
{
    __shared__ __align__(16) unsigned short As[128 * 32];
    __shared__ __align__(16) unsigned short Bs[128 * 32];
    const int t = threadIdx.x;
    const int row0 = blockIdx.x * 128;
    const int wid = t >> 6, lane = t & 63;
    const int wm = (wid >> 1) * 64, wn = (wid & 1) * 64;
    const int qk = (lane >> 4) * 8, r16 = lane & 15;

    const int c0 = t, c1 = t + 256;
    const int am0 = min(row0 + (c0 >> 2), M - 1);
    const int am1 = min(row0 + (c1 >> 2), M - 1);
    const int ak0 = (c0 & 3) * 8, ak1 = (c1 & 3) * 8;
    const int bm0 = c0 >> 2, bm1 = c1 >> 2;          // B has exactly 128 rows

    f32x4 acc[4][4];
#pragma unroll
    for (int i = 0; i < 4; i++)
#pragma unroll
        for (int j = 0; j < 4; j++) acc[i][j] = (f32x4){0.f, 0.f, 0.f, 0.f};

    for (int k0 = 0; k0 < 256; k0 += 32) {
        ASYNC16(A + (size_t)am0 * 256 + k0 + ak0, &As[c0 * 8]);
        ASYNC16(A + (size_t)am1 * 256 + k0 + ak1, &As[c1 * 8]);
        ASYNC16(Bt + (size_t)bm0 * 256 + k0 + ak0, &Bs[c0 * 8]);
        ASYNC16(Bt + (size_t)bm1 * 256 + k0 + ak1, &Bs[c1 * 8]);
        __syncthreads();
        short8 av[4], bv[4];
#pragma unroll
        for (int mt = 0; mt < 4; mt++) av[mt] = *(const short8*)(&As[(wm + mt * 16 + r16) * 32 + qk]);
#pragma unroll
        for (int nt = 0; nt < 4; nt++) bv[nt] = *(const short8*)(&Bs[(wn + nt * 16 + r16) * 32 + qk]);
#pragma unroll
        for (int mt = 0; mt < 4; mt++)
#pragma unroll
            for (int nt = 0; nt < 4; nt++)
                acc[mt][nt] = __builtin_amdgcn_mfma_f32_16x16x32_bf16(av[mt], bv[nt], acc[mt][nt], 0, 0, 0);
        __syncthreads();
    }
#pragma unroll
    for (int mt = 0; mt < 4; mt++) {
#pragma unroll
        for (int r = 0; r < 4; r++) {
            int row = row0 + wm + mt * 16 + (lane >> 4) * 4 + r;
            if (row >= M) continue;
#pragma unroll
            for (int nt = 0; nt < 4; nt++) {
                int col = wn + nt * 16 + r16;
                float v = acc[mt][nt][r];
                if (col < 64) {
                    out[(size_t)row * 64 + col] = v + bL1[col];
                } else {
                    out[(size_t)M * 64 + (size_t)row * 64 + (col - 64)] = v + bL2[col - 64];
                }
            }
        }
    }
}

// packed 2xf32 FMA: d = a*b + c in one VALU instr (CDNA packed FP32 pipe)
__device__ inline f32x2 pkfma(f32x2 a, f32x2 b, f32x2 c) {
    f32x2 d;
    asm("v_pk_fma_f32 %0, %1, %2, %3" : "=v"(d) : "v"(a), "v"(b), "v"(c));
    return d;
}

// decode 16 fp8 (uint4) and FMA into a2[8] (f32x2 pairs): 8 cvt + 8 pk_fma
__device__ inline void acc16f8_pk(f32x2* a2, uint4 r, f32x2 wv) {
    a2[0] = pkfma(__builtin_amdgcn_cvt_pk_f32_fp8((int)r.x, false), wv, a2[0]);
    a2[1] = pkfma(__builtin_amdgcn_cvt_pk_f32_fp8((int)r.x, true),  wv, a2[1]);
    a2[2] = pkfma(__builtin_amdgcn_cvt_pk_f32_fp8((int)r.y, false), wv, a2[2]);
    a2[3] = pkfma(__builtin_amdgcn_cvt_pk_f32_fp8((int)r.y, true),  wv, a2[3]);
    a2[4] = pkfma(__builtin_amdgcn_cvt_pk_f32_fp8((int)r.z, false), wv, a2[4]);
    a2[5] = pkfma(__builtin_amdgcn_cvt_pk_f32_fp8((int)r.z, true),  wv, a2[5]);
    a2[6] = pkfma(__builtin_amdgcn_cvt_pk_f32_fp8((int)r.w, false), wv, a2[6]);
    a2[7] = pkfma(__builtin_amdgcn_cvt_pk_f32_fp8((int)r.w, true),  wv, a2[7]);
}

// fp8-row SPMM: out[n][:] = relu(sum_e w_e * sup[src_e][:] + bias), rows 256B e4m3.
// One wave per node, FOUR 16-lane groups; group g handles edge (chunk*4 + g), lane
// holds 16 features (16B). Depth-3 modulo-scheduled gather ring (chunk = 4 edges):
//   iter k: issue gather chunk k+3, issue idx load chunk k+4, decode chunk k.
// 3 uint4 gathers in flight/lane; decode = 8 cvt_pk + 8 v_pk_fma_f32 per 16B.
// Combine via shfl_xor(16)+(32). Output bf16. (Features sg-permuted transparently.)
__global__ __launch_bounds__(256) void spmm_fp8_kernel(
    const unsigned char* __restrict__ sup, const int* __restrict__ rp,
    const int* __restrict__ esrc, const float* __restrict__ ew,
    const float* __restrict__ bias, unsigned short* __restrict__ out,
    int nnodes, int E)
{
    const int wid = threadIdx.x >> 6, lane = threadIdx.x & 63;
    const int node = blockIdx.x * 4 + wid;
    if (node >= nnodes) return;
    const int g = lane >> 4;            // 0..3
    const int f16 = (lane & 15) * 16;   // feature index (and byte offset)
    const unsigned char* supf = sup + f16;
    const int beg = rp[node], end = rp[node + 1];
    const int Emax = E - 1;

    f32x2 a2[8];
#pragma unroll
    for (int i = 0; i < 8; i++) a2[i] = (f32x2){0.f, 0.f};

    int e = beg;
    const int nmain = (end - beg) >> 2;     // 4-edge chunks (wave-uniform)
    if (nmain > 0) {
        // prologue: idx for chunks 0..3 (clamped), gathers for chunks 0..2
        int p0 = esrc[min(e + g, Emax)];
        int p1 = esrc[min(e + 4 + g, Emax)];
        int p2 = esrc[min(e + 8 + g, Emax)];
        int p3 = esrc[min(e + 12 + g, Emax)];
        float w0 = ew[min(e + g, Emax)];
        float w1 = ew[min(e + 4 + g, Emax)];
        float w2 = ew[min(e + 8 + g, Emax)];
        float w3 = ew[min(e + 12 + g, Emax)];
        uint4 r0 = *(const uint4*)(supf + (size_t)p0 * 256);
        uint4 r1 = *(const uint4*)(supf + (size_t)p1 * 256);
        uint4 r2 = *(const uint4*)(supf + (size_t)p2 * 256);
        for (int k = 0; k < nmain; ++k) {
            const uint4 r3 = *(const uint4*)(supf + (size_t)p3 * 256);  // chunk k+3 (in flight)
            const int   p4 = esrc[min(e + 16 + g, Emax)];               // chunk k+4 idx
            const float w4 = ew[min(e + 16 + g, Emax)];
            const f32x2 wv = (f32x2){w0, w0};
            acc16f8_pk(a2, r0, wv);                                     // decode chunk k
            r0 = r1; r1 = r2; r2 = r3;
            w0 = w1; w1 = w2; w2 = w3; w3 = w4;
            p3 = p4;
            e += 4;
        }
    }
    {
        const int rem = end - e;            // 0..3
        if (g < rem) {
            const int s = esrc[e + g];
            const float w = ew[e + g];
            const uint4 r = *(const uint4*)(supf + (size_t)s * 256);
            acc16f8_pk(a2, r, (f32x2){w, w});
        }
    }

    float a[16];
#pragma unroll
    for (int i = 0; i < 8; i++) { a[2 * i] = a2[i].x; a[2 * i + 1] = a2[i].y; }
#pragma unroll
    for (int i = 0; i < 16; i++) {
        a[i] += __shfl_xor(a[i], 16);
        a[i] += __shfl_xor(a[i], 32);
    }

    if (g == 0) {
        const float4 b0 = *(const float4*)(bias + f16);
        const float4 b1 = *(const float4*)(bias + f16 + 4);
        const float4 b2 = *(const float4*)(bias + f16 + 8);
        const float4 b3 = *(const float4*)(bias + f16 + 12);
        a[0] += b0.x; a[1] += b0.y; a[2]  += b0.z; a[3]  += b0.w;
        a[4] += b1.x; a[5] += b1.y; a[6]  += b1.z; a[7]  += b1.w;
        a[8] += b2.x; a[9] += b2.y; a[10] += b2.z; a[11] += b2.w;
        a[12] += b3.x; a[13] += b3.y; a[14] += b3.z; a[15] += b3.w;
#pragma unroll
        for (int i = 0; i < 16; i++) a[i] = a[i] > 0.f ? a[i] : 0.f;
        uint4 o0, o1;
        o0.x = (unsigned int)f2bf(a[0])  | ((unsigned int)f2bf(a[1])  << 16);
        o0.y = (unsigned int)f2bf(a[2])  | ((unsigned int)f2bf(a[3])  << 16);
        o0.z = (unsigned int)f2bf(a[4])  | ((unsigned int)f2bf(a[5])  << 16);
        o0.w = (unsigned int)f2bf(a[6])  | ((unsigned int)f2bf(a[7])  << 16);
        o1.x = (unsigned int)f2bf(a[8])  | ((unsigned int)f2bf(a[9])  << 16);
        o1.y = (unsigned int)f2bf(a[10]) | ((unsigned int)f2bf(a[11]) << 16);
        o1.z = (unsigned int)f2bf(a[12]) | ((unsigned int)f2bf(a[13]) << 16);
        o1.w = (unsigned int)f2bf(a[14]) | ((unsigned int)f2bf(a[15]) << 16);
        *(uint4*)(out + (size_t)node * 256 + f16) = o0;
        *(uint4*)(out + (size_t)node * 256 + f16 + 8) = o1;
    }
}

extern "C" void kernel_launch(void* const* d_in, const int* in_sizes, int n_in,
                              void* d_out, int out_size, void* d_ws, size_t ws_size,
                              hipStream_t stream) {
    const float* x    = (const float*)d_in[0];
    const int*   esrc = (const int*)d_in[1];
    const int*   edst = (const int*)d_in[2];
    const float* ew   = (const float*)d_in[3];
    const float* W1   = (const float*)d_in[4];
    const float* b1   = (const float*)d_in[5];
    const float* W2   = (const float*)d_in[6];
    const float* b2   = (const float*)d_in[7];
    const float* WL1  = (const float*)d_in[8];
    const float* bL1  = (const float*)d_in[9];
    const float* WL2  = (const float*)d_in[10];
    const float* bL2  = (const float*)d_in[11];
    float* out = (float*)d_out;

    const int N = in_sizes[0] / 256;   // 100000
    const int E = in_sizes[1];         // 3200000

    char* ws = (char*)d_ws;
    size_t off = 0;
    auto alloc = [&](size_t bytes) -> void* {
        void* p = ws + off;
        off = (off + bytes + 511) & ~(size_t)511;   // 512B-align: rows stay line-aligned
        return p;
    };
    int* rp              = (int*)alloc((size_t)(N + 1) * 4);
    unsigned short* W1t  = (unsigned short*)alloc((size_t)256 * 256 * 2);
    unsigned short* W2t  = (unsigned short*)alloc((size_t)256 * 256 * 2);
    unsigned short* WLt  = (unsigned short*)alloc((size_t)128 * 256 * 2);
    float* b1p           = (float*)alloc(256 * 4);
    float* b2p           = (float*)alloc(256 * 4);
    unsigned char* sup8  = (unsigned char*)alloc((size_t)N * 256);      // fp8 support (both layers)
    unsigned short* hbuf = (unsigned short*)alloc((size_t)N * 256 * 2); // xb, then h1/h2 (aliased:
                                                                        // xb dead once gemm1 done)

    const int mblocks = (N + 127) / 128;

    rowptr_kernel<<<(E + 255) / 256, 256, 0, stream>>>(edst, rp, E, N);
    x2bf_kernel<<<(N * 256 / 8 + 255) / 256, 256, 0, stream>>>(x, hbuf, N * 256 / 8);
    prep_kernel<<<642, 256, 0, stream>>>(W1, W2, WL1, WL2, b1, b2, W1t, W2t, WLt, b1p, b2p);

    // layer 1: support fp8 e4m3 (sg-permuted cols)
    gemm_f8_kernel<<<dim3(2, mblocks), 256, 0, stream>>>(hbuf, W1t, sup8, N);
    spmm_fp8_kernel<<<(N + 3) / 4, 256, 0, stream>>>(sup8, rp, esrc, ew, b1p, hbuf, N, E);
    // layer 2 (W2t k-rows pre-permuted to consume sg order; output sg-permuted again)
    gemm_f8_kernel<<<dim3(2, mblocks), 256, 0, stream>>>(hbuf, W2t, sup8, N);
    spmm_fp8_kernel<<<(N + 3) / 4, 256, 0, stream>>>(sup8, rp, esrc, ew, b2p, hbuf, N, E);
    head_kernel<<<mblocks, 256, 0, stream>>>(hbuf, WLt, bL1, bL2, out, N);
}

// Round 8
// 506.181 us; speedup vs baseline: 1.2716x; 1.0401x over previous
//
#include <hip/hip_runtime.h>
#include <hip/hip_bf16.h>

typedef __attribute__((ext_vector_type(8))) short short8;
typedef __attribute__((ext_vector_type(4))) float f32x4;
typedef __attribute__((ext_vector_type(2))) float f32x2;

__device__ inline unsigned short f2bf(float f) {
    union { float f; unsigned int u; } x; x.f = f;
    return (unsigned short)((x.u + 0x7fffu + ((x.u >> 16) & 1u)) >> 16);
}

// async global->LDS, 16B per lane. LDS dest must be wave-uniform base + lane*16.
#define ASYNC16(gptr, lptr)                                                      \
    __builtin_amdgcn_global_load_lds(                                            \
        (const __attribute__((address_space(1))) unsigned int*)(gptr),           \
        (__attribute__((address_space(3))) unsigned int*)(lptr), 16, 0, 0)

// feature permutation (per 64-block): stored position p holds original feature sg(p)
__device__ __host__ inline int sg(int j) {
    int p = j & 63;
    return (j & ~63) | ((p >> 2) + 16 * (p & 3));
}

// rp[n] = lower_bound(dst, n) via boundary diff (dst sorted). One streamed pass.
__global__ void rowptr_kernel(const int* __restrict__ dst, int* __restrict__ rp,
                              int E, int N) {
    int e = blockIdx.x * blockDim.x + threadIdx.x;
    if (e >= E) return;
    int d1 = dst[e];
    int d0 = (e == 0) ? -1 : dst[e - 1];
    for (int n = d0 + 1; n <= d1; n++) rp[n] = e;
    if (e <= N) {                      // tail: nodes past the last dst value
        int dlast = dst[E - 1];
        if (e > dlast) rp[e] = E;
    }
}

// pack (src:17b | bf16 weight sans sign:15b) into one u32, 4 edges/thread.
// weights >= 0 so the sign bit is free; bf16 rel err 2^-9 << fp8 row quant.
__global__ void epack_kernel(const int* __restrict__ src, const float* __restrict__ w,
                             unsigned int* __restrict__ ep, int E4) {
    int i = blockIdx.x * blockDim.x + threadIdx.x;
    if (i >= E4) return;
    const int4 sv = ((const int4*)src)[i];
    const float4 wv = ((const float4*)w)[i];
    uint4 o;
    o.x = ((unsigned int)(f2bf(wv.x) & 0x7fffu) << 17) | (unsigned int)sv.x;
    o.y = ((unsigned int)(f2bf(wv.y) & 0x7fffu) << 17) | (unsigned int)sv.y;
    o.z = ((unsigned int)(f2bf(wv.z) & 0x7fffu) << 17) | (unsigned int)sv.z;
    o.w = ((unsigned int)(f2bf(wv.w) & 0x7fffu) << 17) | (unsigned int)sv.w;
    ((uint4*)ep)[i] = o;
}

__device__ inline float unpackw(unsigned int p) {
    return __uint_as_float((p >> 17) << 16);   // bf16 sans sign -> f32
}

// x fp32 -> bf16 (round-half-up), 8 elements/thread
__global__ void x2bf_kernel(const float* __restrict__ x, unsigned short* __restrict__ xb,
                            int n8) {
    int i = blockIdx.x * blockDim.x + threadIdx.x;
    if (i >= n8) return;
    const uint4* p = (const uint4*)(x + (size_t)i * 8);
    uint4 u = p[0], v = p[1];
    uint4 pk;
    pk.x = ((u.x + 0x8000u) >> 16) | ((u.y + 0x8000u) & 0xffff0000u);
    pk.y = ((u.z + 0x8000u) >> 16) | ((u.w + 0x8000u) & 0xffff0000u);
    pk.z = ((v.x + 0x8000u) >> 16) | ((v.y + 0x8000u) & 0xffff0000u);
    pk.w = ((v.z + 0x8000u) >> 16) | ((v.w + 0x8000u) & 0xffff0000u);
    *(uint4*)(xb + (size_t)i * 8) = pk;
}

// Weight/bias prep. blocks 0..255 -> W1t (k not permuted), 256..511 -> W2t (k sg-permuted),
// 512..639 -> WLt (k sg-permuted), 640 -> b1p, 641 -> b2p (sg-permuted biases).
__global__ void prep_kernel(const float* __restrict__ W1, const float* __restrict__ W2,
                            const float* __restrict__ WL1, const float* __restrict__ WL2,
                            const float* __restrict__ b1, const float* __restrict__ b2,
                            unsigned short* __restrict__ W1t, unsigned short* __restrict__ W2t,
                            unsigned short* __restrict__ WLt,
                            float* __restrict__ b1p, float* __restrict__ b2p) {
    int b = blockIdx.x, k = threadIdx.x;
    if (b < 256) {
        W1t[(size_t)b * 256 + k] = f2bf(W1[(size_t)k * 256 + b]);
    } else if (b < 512) {
        int n = b - 256;
        W2t[(size_t)n * 256 + k] = f2bf(W2[(size_t)sg(k) * 256 + n]);
    } else if (b < 640) {
        int c = b - 512;
        int ks = sg(k);
        float v = (c < 64) ? WL1[(size_t)ks * 64 + c] : WL2[(size_t)ks * 64 + (c - 64)];
        WLt[(size_t)c * 256 + k] = f2bf(v);
    } else if (b == 640) {
        b1p[k] = b1[sg(k)];
    } else {
        b2p[k] = b2[sg(k)];
    }
}

// C8[M][256] fp8 = A[M][256](bf16) @ Bt^T, output columns sg-permuted per 64-block.
// m97-style: global_load_lds staging (16B/lane), unpadded LDS [128][32].
__global__ __launch_bounds__(256) void gemm_f8_kernel(
    const unsigned short* __restrict__ A, const unsigned short* __restrict__ Bt,
    unsigned char* __restrict__ C, int M)
{
    __shared__ __align__(16) unsigned short As[128 * 32];
    __shared__ __align__(16) unsigned short Bs[128 * 32];
    const int t = threadIdx.x;
    const int row0 = blockIdx.y * 128;
    const int col0 = blockIdx.x * 128;
    const int wid = t >> 6, lane = t & 63;
    const int wm = (wid >> 1) * 64, wn = (wid & 1) * 64;
    const int qk = (lane >> 4) * 8, r16 = lane & 15;

    // staging chunks: c covers (m = c>>2, ko = (c&3)*8); LDS offset = c*16B (lane-contiguous)
    const int c0 = t, c1 = t + 256;
    const int am0 = min(row0 + (c0 >> 2), M - 1);
    const int am1 = min(row0 + (c1 >> 2), M - 1);
    const int ak0 = (c0 & 3) * 8, ak1 = (c1 & 3) * 8;
    const int bm0 = col0 + (c0 >> 2), bm1 = col0 + (c1 >> 2);

    f32x4 acc[4][4];
#pragma unroll
    for (int i = 0; i < 4; i++)
#pragma unroll
        for (int j = 0; j < 4; j++) acc[i][j] = (f32x4){0.f, 0.f, 0.f, 0.f};

    for (int k0 = 0; k0 < 256; k0 += 32) {
        ASYNC16(A + (size_t)am0 * 256 + k0 + ak0, &As[c0 * 8]);
        ASYNC16(A + (size_t)am1 * 256 + k0 + ak1, &As[c1 * 8]);
        ASYNC16(Bt + (size_t)bm0 * 256 + k0 + ak0, &Bs[c0 * 8]);
        ASYNC16(Bt + (size_t)bm1 * 256 + k0 + ak1, &Bs[c1 * 8]);
        __syncthreads();
        short8 av[4], bv[4];
#pragma unroll
        for (int mt = 0; mt < 4; mt++) av[mt] = *(const short8*)(&As[(wm + mt * 16 + r16) * 32 + qk]);
#pragma unroll
        for (int nt = 0; nt < 4; nt++) bv[nt] = *(const short8*)(&Bs[(wn + nt * 16 + r16) * 32 + qk]);
#pragma unroll
        for (int mt = 0; mt < 4; mt++)
#pragma unroll
            for (int nt = 0; nt < 4; nt++)
                acc[mt][nt] = __builtin_amdgcn_mfma_f32_16x16x32_bf16(av[mt], bv[nt], acc[mt][nt], 0, 0, 0);
        __syncthreads();
    }
    // permuted fp8 epilogue: lane packs its 4 cols of one row into one dword.
    // stored[col0 + wn + r16*4 + nt] = fp8(orig col0 + wn + nt*16 + r16)  == sg-permutation
#pragma unroll
    for (int mt = 0; mt < 4; mt++) {
        const int rowb = row0 + wm + mt * 16 + (lane >> 4) * 4;
#pragma unroll
        for (int r = 0; r < 4; r++) {
            const int row = rowb + r;
            if (row >= M) continue;
            int w = 0;
            w = __builtin_amdgcn_cvt_pk_fp8_f32(acc[mt][0][r], acc[mt][1][r], w, false);
            w = __builtin_amdgcn_cvt_pk_fp8_f32(acc[mt][2][r], acc[mt][3][r], w, true);
            *(unsigned int*)(C + (size_t)row * 256 + col0 + wn + r16 * 4) = (unsigned int)w;
        }
    }
}

// logits = h2 @ WLt^T + bias (WLt k-dim pre-permuted to match h2's sg order).
// cols 0..63 -> out0, 64..127 -> out1 (concatenated). Same m97 staging.
__global__ __launch_bounds__(256) void head_kernel(
    const unsigned short* __restrict__ A, const unsigned short* __restrict__ Bt,
    const float* __restrict__ bL1, const float* __restrict__ bL2,
    float* __restrict__ out, int M)
{
    __shared__ __align__(16) unsigned short As[128 * 32];
    __shared__ __align__(16) unsigned short Bs[128 * 32];
    const int t = threadIdx.x;
    const int row0 = blockIdx.x * 128;
    const int wid = t >> 6, lane = t & 63;
    const int wm = (wid >> 1) * 64, wn = (wid & 1) * 64;
    const int qk = (lane >> 4) * 8, r16 = lane & 15;

    const int c0 = t, c1 = t + 256;
    const int am0 = min(row0 + (c0 >> 2), M - 1);
    const int am1 = min(row0 + (c1 >> 2), M - 1);
    const int ak0 = (c0 & 3) * 8, ak1 = (c1 & 3) * 8;
    const int bm0 = c0 >> 2, bm1 = c1 >> 2;          // B has exactly 128 rows

    f32x4 acc[4][4];
#pragma unroll
    for (int i = 0; i < 4; i++)
#pragma unroll
        for (int j = 0; j < 4; j++) acc[i][j] = (f32x4){0.f, 0.f, 0.f, 0.f};

    for (int k0 = 0; k0 < 256; k0 += 32) {
        ASYNC16(A + (size_t)am0 * 256 + k0 + ak0, &As[c0 * 8]);
        ASYNC16(A + (size_t)am1 * 256 + k0 + ak1, &As[c1 * 8]);
        ASYNC16(Bt + (size_t)bm0 * 256 + k0 + ak0, &Bs[c0 * 8]);
        ASYNC16(Bt + (size_t)bm1 * 256 + k0 + ak1, &Bs[c1 * 8]);
        __syncthreads();
        short8 av[4], bv[4];
#pragma unroll
        for (int mt = 0; mt < 4; mt++) av[mt] = *(const short8*)(&As[(wm + mt * 16 + r16) * 32 + qk]);
#pragma unroll
        for (int nt = 0; nt < 4; nt++) bv[nt] = *(const short8*)(&Bs[(wn + nt * 16 + r16) * 32 + qk]);
#pragma unroll
        for (int mt = 0; mt < 4; mt++)
#pragma unroll
            for (int nt = 0; nt < 4; nt++)
                acc[mt][nt] = __builtin_amdgcn_mfma_f32_16x16x32_bf16(av[mt], bv[nt], acc[mt][nt], 0, 0, 0);
        __syncthreads();
    }
#pragma unroll
    for (int mt = 0; mt < 4; mt++) {
#pragma unroll
        for (int r = 0; r < 4; r++) {
            int row = row0 + wm + mt * 16 + (lane >> 4) * 4 + r;
            if (row >= M) continue;
#pragma unroll
            for (int nt = 0; nt < 4; nt++) {
                int col = wn + nt * 16 + r16;
                float v = acc[mt][nt][r];
                if (col < 64) {
                    out[(size_t)row * 64 + col] = v + bL1[col];
                } else {
                    out[(size_t)M * 64 + (size_t)row * 64 + (col - 64)] = v + bL2[col - 64];
                }
            }
        }
    }
}

// decode 16 fp8 (uint4) and FMA into a[16]
__device__ inline void acc16f8(float* a, uint4 r, float w) {
    f32x2 p;
    p = __builtin_amdgcn_cvt_pk_f32_fp8((int)r.x, false); a[0]  += w * p.x; a[1]  += w * p.y;
    p = __builtin_amdgcn_cvt_pk_f32_fp8((int)r.x, true);  a[2]  += w * p.x; a[3]  += w * p.y;
    p = __builtin_amdgcn_cvt_pk_f32_fp8((int)r.y, false); a[4]  += w * p.x; a[5]  += w * p.y;
    p = __builtin_amdgcn_cvt_pk_f32_fp8((int)r.y, true);  a[6]  += w * p.x; a[7]  += w * p.y;
    p = __builtin_amdgcn_cvt_pk_f32_fp8((int)r.z, false); a[8]  += w * p.x; a[9]  += w * p.y;
    p = __builtin_amdgcn_cvt_pk_f32_fp8((int)r.z, true);  a[10] += w * p.x; a[11] += w * p.y;
    p = __builtin_amdgcn_cvt_pk_f32_fp8((int)r.w, false); a[12] += w * p.x; a[13] += w * p.y;
    p = __builtin_amdgcn_cvt_pk_f32_fp8((int)r.w, true);  a[14] += w * p.x; a[15] += w * p.y;
}

// fp8-row SPMM: out[n][:] = relu(sum_e w_e * sup[src_e][:] + bias), rows 256B e4m3.
// One wave per node, FOUR 16-lane groups; group g handles edge e+g, lane holds
// 16 features (16B). R5's depth-2 modulo schedule (the verified optimum):
//   iter i: issue gathers chunk i+1 (idx resident), issue PACKED edge loads chunk i+2,
//   decode chunk i. 2 gathers in flight/wave. Packed edges: 1 load/edge vs 2.
// Combine via shfl_xor(16) + shfl_xor(32). Output bf16. (Features sg-permuted transparently.)
__global__ __launch_bounds__(256) void spmm_fp8_kernel(
    const unsigned char* __restrict__ sup, const int* __restrict__ rp,
    const unsigned int* __restrict__ ep, const float* __restrict__ bias,
    unsigned short* __restrict__ out, int nnodes)
{
    const int wid = threadIdx.x >> 6, lane = threadIdx.x & 63;
    const int node = blockIdx.x * 4 + wid;
    if (node >= nnodes) return;
    const int g = lane >> 4;            // 0..3
    const int f16 = (lane & 15) * 16;   // feature index (and byte offset)
    const unsigned char* supf = sup + f16;
    const int beg = rp[node], end = rp[node + 1];

    float a[16];
#pragma unroll
    for (int i = 0; i < 16; i++) a[i] = 0.f;

    int e = beg;
    const int nmain = (end - beg) >> 3;     // 8-edge chunks (wave-uniform)
    if (nmain > 0) {
        // prologue: packed edges + gathers for chunk 0; packed edges for chunk 1
        unsigned int cp0 = ep[e + g], cp1 = ep[e + 4 + g];
        uint4 cr0 = *(const uint4*)(supf + (size_t)(cp0 & 0x1ffffu) * 256);
        uint4 cr1 = *(const uint4*)(supf + (size_t)(cp1 & 0x1ffffu) * 256);
        unsigned int np0 = 0, np1 = 0;
        if (nmain > 1) {
            np0 = ep[e + 8 + g]; np1 = ep[e + 12 + g];
        }
        for (int it = 0; it + 1 < nmain; ++it) {
            // issue gathers for chunk it+1 (packed words arrived an iteration ago)
            const uint4 nr0 = *(const uint4*)(supf + (size_t)(np0 & 0x1ffffu) * 256);
            const uint4 nr1 = *(const uint4*)(supf + (size_t)(np1 & 0x1ffffu) * 256);
            // issue packed edge loads for chunk it+2
            unsigned int mp0 = 0, mp1 = 0;
            if (it + 2 < nmain) {
                const int eb = e + (it + 2) * 8;
                mp0 = ep[eb + g]; mp1 = ep[eb + 4 + g];
            }
            // decode chunk it (waits only on cr0/cr1; nr + mp stay in flight)
            acc16f8(a, cr0, unpackw(cp0));
            acc16f8(a, cr1, unpackw(cp1));
            cr0 = nr0; cr1 = nr1; cp0 = np0; cp1 = np1;
            np0 = mp0; np1 = mp1;
        }
        acc16f8(a, cr0, unpackw(cp0));
        acc16f8(a, cr1, unpackw(cp1));
        e += nmain * 8;
    }
    for (; e + 4 <= end; e += 4) {
        const unsigned int p = ep[e + g];
        const uint4 r = *(const uint4*)(supf + (size_t)(p & 0x1ffffu) * 256);
        acc16f8(a, r, unpackw(p));
    }
    {
        const int rem = end - e;         // 0..3
        if (g < rem) {
            const unsigned int p = ep[e + g];
            const uint4 r = *(const uint4*)(supf + (size_t)(p & 0x1ffffu) * 256);
            acc16f8(a, r, unpackw(p));
        }
    }
#pragma unroll
    for (int i = 0; i < 16; i++) {
        a[i] += __shfl_xor(a[i], 16);
        a[i] += __shfl_xor(a[i], 32);
    }

    if (g == 0) {
        const float4 b0 = *(const float4*)(bias + f16);
        const float4 b1 = *(const float4*)(bias + f16 + 4);
        const float4 b2 = *(const float4*)(bias + f16 + 8);
        const float4 b3 = *(const float4*)(bias + f16 + 12);
        a[0] += b0.x; a[1] += b0.y; a[2]  += b0.z; a[3]  += b0.w;
        a[4] += b1.x; a[5] += b1.y; a[6]  += b1.z; a[7]  += b1.w;
        a[8] += b2.x; a[9] += b2.y; a[10] += b2.z; a[11] += b2.w;
        a[12] += b3.x; a[13] += b3.y; a[14] += b3.z; a[15] += b3.w;
#pragma unroll
        for (int i = 0; i < 16; i++) a[i] = a[i] > 0.f ? a[i] : 0.f;
        uint4 o0, o1;
        o0.x = (unsigned int)f2bf(a[0])  | ((unsigned int)f2bf(a[1])  << 16);
        o0.y = (unsigned int)f2bf(a[2])  | ((unsigned int)f2bf(a[3])  << 16);
        o0.z = (unsigned int)f2bf(a[4])  | ((unsigned int)f2bf(a[5])  << 16);
        o0.w = (unsigned int)f2bf(a[6])  | ((unsigned int)f2bf(a[7])  << 16);
        o1.x = (unsigned int)f2bf(a[8])  | ((unsigned int)f2bf(a[9])  << 16);
        o1.y = (unsigned int)f2bf(a[10]) | ((unsigned int)f2bf(a[11]) << 16);
        o1.z = (unsigned int)f2bf(a[12]) | ((unsigned int)f2bf(a[13]) << 16);
        o1.w = (unsigned int)f2bf(a[14]) | ((unsigned int)f2bf(a[15]) << 16);
        *(uint4*)(out + (size_t)node * 256 + f16) = o0;
        *(uint4*)(out + (size_t)node * 256 + f16 + 8) = o1;
    }
}

// fallback spmm (raw esrc/ew) if the packed-edge array doesn't fit the workspace.
__global__ __launch_bounds__(256) void spmm_fp8_raw_kernel(
    const unsigned char* __restrict__ sup, const int* __restrict__ rp,
    const int* __restrict__ esrc, const float* __restrict__ ew,
    const float* __restrict__ bias, unsigned short* __restrict__ out, int nnodes)
{
    const int wid = threadIdx.x >> 6, lane = threadIdx.x & 63;
    const int node = blockIdx.x * 4 + wid;
    if (node >= nnodes) return;
    const int g = lane >> 4;
    const int f16 = (lane & 15) * 16;
    const unsigned char* supf = sup + f16;
    const int beg = rp[node], end = rp[node + 1];

    float a[16];
#pragma unroll
    for (int i = 0; i < 16; i++) a[i] = 0.f;

    int e = beg;
    for (; e + 8 <= end; e += 8) {
        const int s0 = esrc[e + g],     s1 = esrc[e + 4 + g];
        const float w0 = ew[e + g],     w1 = ew[e + 4 + g];
        const uint4 r0 = *(const uint4*)(supf + (size_t)s0 * 256);
        const uint4 r1 = *(const uint4*)(supf + (size_t)s1 * 256);
        acc16f8(a, r0, w0);
        acc16f8(a, r1, w1);
    }
    for (; e + 4 <= end; e += 4) {
        const int s = esrc[e + g];
        const float w = ew[e + g];
        const uint4 r = *(const uint4*)(supf + (size_t)s * 256);
        acc16f8(a, r, w);
    }
    {
        const int rem = end - e;
        if (g < rem) {
            const int s = esrc[e + g];
            const float w = ew[e + g];
            const uint4 r = *(const uint4*)(supf + (size_t)s * 256);
            acc16f8(a, r, w);
        }
    }
#pragma unroll
    for (int i = 0; i < 16; i++) {
        a[i] += __shfl_xor(a[i], 16);
        a[i] += __shfl_xor(a[i], 32);
    }

    if (g == 0) {
        const float4 b0 = *(const float4*)(bias + f16);
        const float4 b1 = *(const float4*)(bias + f16 + 4);
        const float4 b2 = *(const float4*)(bias + f16 + 8);
        const float4 b3 = *(const float4*)(bias + f16 + 12);
        a[0] += b0.x; a[1] += b0.y; a[2]  += b0.z; a[3]  += b0.w;
        a[4] += b1.x; a[5] += b1.y; a[6]  += b1.z; a[7]  += b1.w;
        a[8] += b2.x; a[9] += b2.y; a[10] += b2.z; a[11] += b2.w;
        a[12] += b3.x; a[13] += b3.y; a[14] += b3.z; a[15] += b3.w;
#pragma unroll
        for (int i = 0; i < 16; i++) a[i] = a[i] > 0.f ? a[i] : 0.f;
        uint4 o0, o1;
        o0.x = (unsigned int)f2bf(a[0])  | ((unsigned int)f2bf(a[1])  << 16);
        o0.y = (unsigned int)f2bf(a[2])  | ((unsigned int)f2bf(a[3])  << 16);
        o0.z = (unsigned int)f2bf(a[4])  | ((unsigned int)f2bf(a[5])  << 16);
        o0.w = (unsigned int)f2bf(a[6])  | ((unsigned int)f2bf(a[7])  << 16);
        o1.x = (unsigned int)f2bf(a[8])  | ((unsigned int)f2bf(a[9])  << 16);
        o1.y = (unsigned int)f2bf(a[10]) | ((unsigned int)f2bf(a[11]) << 16);
        o1.z = (unsigned int)f2bf(a[12]) | ((unsigned int)f2bf(a[13]) << 16);
        o1.w = (unsigned int)f2bf(a[14]) | ((unsigned int)f2bf(a[15]) << 16);
        *(uint4*)(out + (size_t)node * 256 + f16) = o0;
        *(uint4*)(out + (size_t)node * 256 + f16 + 8) = o1;
    }
}

extern "C" void kernel_launch(void* const* d_in, const int* in_sizes, int n_in,
                              void* d_out, int out_size, void* d_ws, size_t ws_size,
                              hipStream_t stream) {
    const float* x    = (const float*)d_in[0];
    const int*   esrc = (const int*)d_in[1];
    const int*   edst = (const int*)d_in[2];
    const float* ew   = (const float*)d_in[3];
    const float* W1   = (const float*)d_in[4];
    const float* b1   = (const float*)d_in[5];
    const float* W2   = (const float*)d_in[6];
    const float* b2   = (const float*)d_in[7];
    const float* WL1  = (const float*)d_in[8];
    const float* bL1  = (const float*)d_in[9];
    const float* WL2  = (const float*)d_in[10];
    const float* bL2  = (const float*)d_in[11];
    float* out = (float*)d_out;

    const int N = in_sizes[0] / 256;   // 100000
    const int E = in_sizes[1];         // 3200000

    char* ws = (char*)d_ws;
    size_t off = 0;
    auto alloc = [&](size_t bytes) -> void* {
        void* p = ws + off;
        off = (off + bytes + 511) & ~(size_t)511;   // 512B-align: rows stay line-aligned
        return p;
    };
    int* rp              = (int*)alloc((size_t)(N + 1) * 4);
    unsigned short* W1t  = (unsigned short*)alloc((size_t)256 * 256 * 2);
    unsigned short* W2t  = (unsigned short*)alloc((size_t)256 * 256 * 2);
    unsigned short* WLt  = (unsigned short*)alloc((size_t)128 * 256 * 2);
    float* b1p           = (float*)alloc(256 * 4);
    float* b2p           = (float*)alloc(256 * 4);
    unsigned char* sup8  = (unsigned char*)alloc((size_t)N * 256);      // fp8 support (both layers)
    unsigned short* hbuf = (unsigned short*)alloc((size_t)N * 256 * 2); // xb, then h1/h2 (aliased)
    unsigned int* ep     = (unsigned int*)alloc((size_t)E * 4);         // packed edges (LAST alloc)
    const bool packed = (off <= ws_size);   // ws overflow guard: fall back to raw esrc/ew

    const int mblocks = (N + 127) / 128;

    rowptr_kernel<<<(E + 255) / 256, 256, 0, stream>>>(edst, rp, E, N);
    if (packed)
        epack_kernel<<<(E / 4 + 255) / 256, 256, 0, stream>>>(esrc, ew, ep, E / 4);
    x2bf_kernel<<<(N * 256 / 8 + 255) / 256, 256, 0, stream>>>(x, hbuf, N * 256 / 8);
    prep_kernel<<<642, 256, 0, stream>>>(W1, W2, WL1, WL2, b1, b2, W1t, W2t, WLt, b1p, b2p);

    // layer 1: support fp8 e4m3 (sg-permuted cols)
    gemm_f8_kernel<<<dim3(2, mblocks), 256, 0, stream>>>(hbuf, W1t, sup8, N);
    if (packed)
        spmm_fp8_kernel<<<(N + 3) / 4, 256, 0, stream>>>(sup8, rp, ep, b1p, hbuf, N);
    else
        spmm_fp8_raw_kernel<<<(N + 3) / 4, 256, 0, stream>>>(sup8, rp, esrc, ew, b1p, hbuf, N);
    // layer 2 (W2t k-rows pre-permuted to consume sg order; output sg-permuted again)
    gemm_f8_kernel<<<dim3(2, mblocks), 256, 0, stream>>>(hbuf, W2t, sup8, N);
    if (packed)
        spmm_fp8_kernel<<<(N + 3) / 4, 256, 0, stream>>>(sup8, rp, ep, b2p, hbuf, N);
    else
        spmm_fp8_raw_kernel<<<(N + 3) / 4, 256, 0, stream>>>(sup8, rp, esrc, ew, b2p, hbuf, N);
    head_kernel<<<mblocks, 256, 0, stream>>>(hbuf, WLt, bL1, bL2, out, N);
}

// Round 9
// 483.067 us; speedup vs baseline: 1.3324x; 1.0478x over previous
//
#include <hip/hip_runtime.h>
#include <hip/hip_bf16.h>

typedef __attribute__((ext_vector_type(8))) short short8;
typedef __attribute__((ext_vector_type(4))) float f32x4;
typedef __attribute__((ext_vector_type(2))) float f32x2;

__device__ inline unsigned short f2bf(float f) {
    union { float f; unsigned int u; } x; x.f = f;
    return (unsigned short)((x.u + 0x7fffu + ((x.u >> 16) & 1u)) >> 16);
}

// async global->LDS, 16B per lane. LDS dest must be wave-uniform base + lane*16.
#define ASYNC16(gptr, lptr)                                                      \
    __builtin_amdgcn_global_load_lds(                                            \
        (const __attribute__((address_space(1))) unsigned int*)(gptr),           \
        (__attribute__((address_space(3))) unsigned int*)(lptr), 16, 0, 0)

// feature permutation (per 64-block): stored position p holds original feature sg(p)
__device__ __host__ inline int sg(int j) {
    int p = j & 63;
    return (j & ~63) | ((p >> 2) + 16 * (p & 3));
}

// rp[n] = lower_bound(dst, n) via boundary diff (dst sorted). One streamed pass.
__global__ void rowptr_kernel(const int* __restrict__ dst, int* __restrict__ rp,
                              int E, int N) {
    int e = blockIdx.x * blockDim.x + threadIdx.x;
    if (e >= E) return;
    int d1 = dst[e];
    int d0 = (e == 0) ? -1 : dst[e - 1];
    for (int n = d0 + 1; n <= d1; n++) rp[n] = e;
    if (e <= N) {                      // tail: nodes past the last dst value
        int dlast = dst[E - 1];
        if (e > dlast) rp[e] = E;
    }
}

// pack (src:17b | bf16 weight sans sign:15b) into one u32, 4 edges/thread.
// weights >= 0 so the sign bit is free; bf16 rel err 2^-9 << fp8 row quant.
__global__ void epack_kernel(const int* __restrict__ src, const float* __restrict__ w,
                             unsigned int* __restrict__ ep, int E4) {
    int i = blockIdx.x * blockDim.x + threadIdx.x;
    if (i >= E4) return;
    const int4 sv = ((const int4*)src)[i];
    const float4 wv = ((const float4*)w)[i];
    uint4 o;
    o.x = ((unsigned int)(f2bf(wv.x) & 0x7fffu) << 17) | (unsigned int)sv.x;
    o.y = ((unsigned int)(f2bf(wv.y) & 0x7fffu) << 17) | (unsigned int)sv.y;
    o.z = ((unsigned int)(f2bf(wv.z) & 0x7fffu) << 17) | (unsigned int)sv.z;
    o.w = ((unsigned int)(f2bf(wv.w) & 0x7fffu) << 17) | (unsigned int)sv.w;
    ((uint4*)ep)[i] = o;
}

__device__ inline float unpackw(unsigned int p) {
    return __uint_as_float((p >> 17) << 16);   // bf16 sans sign -> f32
}

// Weight/bias prep. blocks 0..255 -> W1t (k not permuted), 256..511 -> W2t (k sg-permuted),
// 512..639 -> WLt (k sg-permuted), 640 -> b1p, 641 -> b2p (sg-permuted biases).
__global__ void prep_kernel(const float* __restrict__ W1, const float* __restrict__ W2,
                            const float* __restrict__ WL1, const float* __restrict__ WL2,
                            const float* __restrict__ b1, const float* __restrict__ b2,
                            unsigned short* __restrict__ W1t, unsigned short* __restrict__ W2t,
                            unsigned short* __restrict__ WLt,
                            float* __restrict__ b1p, float* __restrict__ b2p) {
    int b = blockIdx.x, k = threadIdx.x;
    if (b < 256) {
        W1t[(size_t)b * 256 + k] = f2bf(W1[(size_t)k * 256 + b]);
    } else if (b < 512) {
        int n = b - 256;
        W2t[(size_t)n * 256 + k] = f2bf(W2[(size_t)sg(k) * 256 + n]);
    } else if (b < 640) {
        int c = b - 512;
        int ks = sg(k);
        float v = (c < 64) ? WL1[(size_t)ks * 64 + c] : WL2[(size_t)ks * 64 + (c - 64)];
        WLt[(size_t)c * 256 + k] = f2bf(v);
    } else if (b == 640) {
        b1p[k] = b1[sg(k)];
    } else {
        b2p[k] = b2[sg(k)];
    }
}

// Layer-1 GEMM with FUSED fp32->bf16 A-staging (x2bf eliminated).
// A = x fp32 [M][256]; each thread loads 8 fp32, packs to bf16 (same bit-twiddle
// as the old x2bf kernel), ds_write_b128 into the SAME LDS layout the MFMA path
// already consumes. B stays global_load_lds. Epilogue identical to gemm_f8_kernel.
__global__ __launch_bounds__(256) void gemm_f8_x32_kernel(
    const float* __restrict__ A, const unsigned short* __restrict__ Bt,
    unsigned char* __restrict__ C, int M)
{
    __shared__ __align__(16) unsigned short As[128 * 32];
    __shared__ __align__(16) unsigned short Bs[128 * 32];
    const int t = threadIdx.x;
    const int row0 = blockIdx.y * 128;
    const int col0 = blockIdx.x * 128;
    const int wid = t >> 6, lane = t & 63;
    const int wm = (wid >> 1) * 64, wn = (wid & 1) * 64;
    const int qk = (lane >> 4) * 8, r16 = lane & 15;

    const int c0 = t, c1 = t + 256;
    const int am0 = min(row0 + (c0 >> 2), M - 1);
    const int am1 = min(row0 + (c1 >> 2), M - 1);
    const int ak0 = (c0 & 3) * 8, ak1 = (c1 & 3) * 8;
    const int bm0 = col0 + (c0 >> 2), bm1 = col0 + (c1 >> 2);

    f32x4 acc[4][4];
#pragma unroll
    for (int i = 0; i < 4; i++)
#pragma unroll
        for (int j = 0; j < 4; j++) acc[i][j] = (f32x4){0.f, 0.f, 0.f, 0.f};

    for (int k0 = 0; k0 < 256; k0 += 32) {
        ASYNC16(Bt + (size_t)bm0 * 256 + k0 + ak0, &Bs[c0 * 8]);
        ASYNC16(Bt + (size_t)bm1 * 256 + k0 + ak1, &Bs[c1 * 8]);
        // A: fp32 -> bf16 reg staging (x2bf's exact pack), ds_write to same layout
        const float* pa0 = A + (size_t)am0 * 256 + k0 + ak0;
        const float* pa1 = A + (size_t)am1 * 256 + k0 + ak1;
        const uint4 u0 = *(const uint4*)pa0, v0 = *(const uint4*)(pa0 + 4);
        const uint4 u1 = *(const uint4*)pa1, v1 = *(const uint4*)(pa1 + 4);
        uint4 pk0, pk1;
        pk0.x = ((u0.x + 0x8000u) >> 16) | ((u0.y + 0x8000u) & 0xffff0000u);
        pk0.y = ((u0.z + 0x8000u) >> 16) | ((u0.w + 0x8000u) & 0xffff0000u);
        pk0.z = ((v0.x + 0x8000u) >> 16) | ((v0.y + 0x8000u) & 0xffff0000u);
        pk0.w = ((v0.z + 0x8000u) >> 16) | ((v0.w + 0x8000u) & 0xffff0000u);
        pk1.x = ((u1.x + 0x8000u) >> 16) | ((u1.y + 0x8000u) & 0xffff0000u);
        pk1.y = ((u1.z + 0x8000u) >> 16) | ((u1.w + 0x8000u) & 0xffff0000u);
        pk1.z = ((v1.x + 0x8000u) >> 16) | ((v1.y + 0x8000u) & 0xffff0000u);
        pk1.w = ((v1.z + 0x8000u) >> 16) | ((v1.w + 0x8000u) & 0xffff0000u);
        *(uint4*)(&As[c0 * 8]) = pk0;
        *(uint4*)(&As[c1 * 8]) = pk1;
        __syncthreads();
        short8 av[4], bv[4];
#pragma unroll
        for (int mt = 0; mt < 4; mt++) av[mt] = *(const short8*)(&As[(wm + mt * 16 + r16) * 32 + qk]);
#pragma unroll
        for (int nt = 0; nt < 4; nt++) bv[nt] = *(const short8*)(&Bs[(wn + nt * 16 + r16) * 32 + qk]);
#pragma unroll
        for (int mt = 0; mt < 4; mt++)
#pragma unroll
            for (int nt = 0; nt < 4; nt++)
                acc[mt][nt] = __builtin_amdgcn_mfma_f32_16x16x32_bf16(av[mt], bv[nt], acc[mt][nt], 0, 0, 0);
        __syncthreads();
    }
    const int scol0 = col0 + wn + r16 * 4;
#pragma unroll
    for (int mt = 0; mt < 4; mt++) {
        const int rowb = row0 + wm + mt * 16 + (lane >> 4) * 4;
#pragma unroll
        for (int r = 0; r < 4; r++) {
            const int row = rowb + r;
            if (row >= M) continue;
            int w = 0;
            w = __builtin_amdgcn_cvt_pk_fp8_f32(acc[mt][0][r], acc[mt][1][r], w, false);
            w = __builtin_amdgcn_cvt_pk_fp8_f32(acc[mt][2][r], acc[mt][3][r], w, true);
            *(unsigned int*)(C + (size_t)row * 256 + scol0) = (unsigned int)w;
        }
    }
}

// C8[M][256] fp8 = A[M][256](bf16) @ Bt^T, output columns sg-permuted per 64-block.
// m97-style: global_load_lds staging (16B/lane), unpadded LDS [128][32].
__global__ __launch_bounds__(256) void gemm_f8_kernel(
    const unsigned short* __restrict__ A, const unsigned short* __restrict__ Bt,
    unsigned char* __restrict__ C, int M)
{
    __shared__ __align__(16) unsigned short As[128 * 32];
    __shared__ __align__(16) unsigned short Bs[128 * 32];
    const int t = threadIdx.x;
    const int row0 = blockIdx.y * 128;
    const int col0 = blockIdx.x * 128;
    const int wid = t >> 6, lane = t & 63;
    const int wm = (wid >> 1) * 64, wn = (wid & 1) * 64;
    const int qk = (lane >> 4) * 8, r16 = lane & 15;

    const int c0 = t, c1 = t + 256;
    const int am0 = min(row0 + (c0 >> 2), M - 1);
    const int am1 = min(row0 + (c1 >> 2), M - 1);
    const int ak0 = (c0 & 3) * 8, ak1 = (c1 & 3) * 8;
    const int bm0 = col0 + (c0 >> 2), bm1 = col0 + (c1 >> 2);

    f32x4 acc[4][4];
#pragma unroll
    for (int i = 0; i < 4; i++)
#pragma unroll
        for (int j = 0; j < 4; j++) acc[i][j] = (f32x4){0.f, 0.f, 0.f, 0.f};

    for (int k0 = 0; k0 < 256; k0 += 32) {
        ASYNC16(A + (size_t)am0 * 256 + k0 + ak0, &As[c0 * 8]);
        ASYNC16(A + (size_t)am1 * 256 + k0 + ak1, &As[c1 * 8]);
        ASYNC16(Bt + (size_t)bm0 * 256 + k0 + ak0, &Bs[c0 * 8]);
        ASYNC16(Bt + (size_t)bm1 * 256 + k0 + ak1, &Bs[c1 * 8]);
        __syncthreads();
        short8 av[4], bv[4];
#pragma unroll
        for (int mt = 0; mt < 4; mt++) av[mt] = *(const short8*)(&As[(wm + mt * 16 + r16) * 32 + qk]);
#pragma unroll
        for (int nt = 0; nt < 4; nt++) bv[nt] = *(const short8*)(&Bs[(wn + nt * 16 + r16) * 32 + qk]);
#pragma unroll
        for (int mt = 0; mt < 4; mt++)
#pragma unroll
            for (int nt = 0; nt < 4; nt++)
                acc[mt][nt] = __builtin_amdgcn_mfma_f32_16x16x32_bf16(av[mt], bv[nt], acc[mt][nt], 0, 0, 0);
        __syncthreads();
    }
#pragma unroll
    for (int mt = 0; mt < 4; mt++) {
        const int rowb = row0 + wm + mt * 16 + (lane >> 4) * 4;
#pragma unroll
        for (int r = 0; r < 4; r++) {
            const int row = rowb + r;
            if (row >= M) continue;
            int w = 0;
            w = __builtin_amdgcn_cvt_pk_fp8_f32(acc[mt][0][r], acc[mt][1][r], w, false);
            w = __builtin_amdgcn_cvt_pk_fp8_f32(acc[mt][2][r], acc[mt][3][r], w, true);
            *(unsigned int*)(C + (size_t)row * 256 + col0 + wn + r16 * 4) = (unsigned int)w;
        }
    }
}

// logits = h2 @ WLt^T + bias (WLt k-dim pre-permuted to match h2's sg order).
__global__ __launch_bounds__(256) void head_kernel(
    const unsigned short* __restrict__ A, const unsigned short* __restrict__ Bt,
    const float* __restrict__ bL1, const float* __restrict__ bL2,
    float* __restrict__ out, int M)
{
    __shared__ __align__(16) unsigned short As[128 * 32];
    __shared__ __align__(16) unsigned short Bs[128 * 32];
    const int t = threadIdx.x;
    const int row0 = blockIdx.x * 128;
    const int wid = t >> 6, lane = t & 63;
    const int wm = (wid >> 1) * 64, wn = (wid & 1) * 64;
    const int qk = (lane >> 4) * 8, r16 = lane & 15;

    const int c0 = t, c1 = t + 256;
    const int am0 = min(row0 + (c0 >> 2), M - 1);
    const int am1 = min(row0 + (c1 >> 2), M - 1);
    const int ak0 = (c0 & 3) * 8, ak1 = (c1 & 3) * 8;
    const int bm0 = c0 >> 2, bm1 = c1 >> 2;          // B has exactly 128 rows

    f32x4 acc[4][4];
#pragma unroll
    for (int i = 0; i < 4; i++)
#pragma unroll
        for (int j = 0; j < 4; j++) acc[i][j] = (f32x4){0.f, 0.f, 0.f, 0.f};

    for (int k0 = 0; k0 < 256; k0 += 32) {
        ASYNC16(A + (size_t)am0 * 256 + k0 + ak0, &As[c0 * 8]);
        ASYNC16(A + (size_t)am1 * 256 + k0 + ak1, &As[c1 * 8]);
        ASYNC16(Bt + (size_t)bm0 * 256 + k0 + ak0, &Bs[c0 * 8]);
        ASYNC16(Bt + (size_t)bm1 * 256 + k0 + ak1, &Bs[c1 * 8]);
        __syncthreads();
        short8 av[4], bv[4];
#pragma unroll
        for (int mt = 0; mt < 4; mt++) av[mt] = *(const short8*)(&As[(wm + mt * 16 + r16) * 32 + qk]);
#pragma unroll
        for (int nt = 0; nt < 4; nt++) bv[nt] = *(const short8*)(&Bs[(wn + nt * 16 + r16) * 32 + qk]);
#pragma unroll
        for (int mt = 0; mt < 4; mt++)
#pragma unroll
            for (int nt = 0; nt < 4; nt++)
                acc[mt][nt] = __builtin_amdgcn_mfma_f32_16x16x32_bf16(av[mt], bv[nt], acc[mt][nt], 0, 0, 0);
        __syncthreads();
    }
#pragma unroll
    for (int mt = 0; mt < 4; mt++) {
#pragma unroll
        for (int r = 0; r < 4; r++) {
            int row = row0 + wm + mt * 16 + (lane >> 4) * 4 + r;
            if (row >= M) continue;
#pragma unroll
            for (int nt = 0; nt < 4; nt++) {
                int col = wn + nt * 16 + r16;
                float v = acc[mt][nt][r];
                if (col < 64) {
                    out[(size_t)row * 64 + col] = v + bL1[col];
                } else {
                    out[(size_t)M * 64 + (size_t)row * 64 + (col - 64)] = v + bL2[col - 64];
                }
            }
        }
    }
}

// packed 2xf32 FMA: d = a*b + c in one VALU instr (CDNA packed FP32 pipe)
__device__ inline f32x2 pkfma(f32x2 a, f32x2 b, f32x2 c) {
    f32x2 d;
    asm("v_pk_fma_f32 %0, %1, %2, %3" : "=v"(d) : "v"(a), "v"(b), "v"(c));
    return d;
}

// decode 16 fp8 (uint4) and FMA into a2[8] (f32x2 pairs): 8 cvt + 8 pk_fma
__device__ inline void acc16f8_pk(f32x2* a2, uint4 r, f32x2 wv) {
    a2[0] = pkfma(__builtin_amdgcn_cvt_pk_f32_fp8((int)r.x, false), wv, a2[0]);
    a2[1] = pkfma(__builtin_amdgcn_cvt_pk_f32_fp8((int)r.x, true),  wv, a2[1]);
    a2[2] = pkfma(__builtin_amdgcn_cvt_pk_f32_fp8((int)r.y, false), wv, a2[2]);
    a2[3] = pkfma(__builtin_amdgcn_cvt_pk_f32_fp8((int)r.y, true),  wv, a2[3]);
    a2[4] = pkfma(__builtin_amdgcn_cvt_pk_f32_fp8((int)r.z, false), wv, a2[4]);
    a2[5] = pkfma(__builtin_amdgcn_cvt_pk_f32_fp8((int)r.z, true),  wv, a2[5]);
    a2[6] = pkfma(__builtin_amdgcn_cvt_pk_f32_fp8((int)r.w, false), wv, a2[6]);
    a2[7] = pkfma(__builtin_amdgcn_cvt_pk_f32_fp8((int)r.w, true),  wv, a2[7]);
}

// fp8-row SPMM: R8's verified depth-2 modulo schedule, decode via v_pk_fma_f32
// (24 -> 16 VALU per 16B; structure otherwise byte-identical to R8's 111.5us kernel).
__global__ __launch_bounds__(256) void spmm_fp8_kernel(
    const unsigned char* __restrict__ sup, const int* __restrict__ rp,
    const unsigned int* __restrict__ ep, const float* __restrict__ bias,
    unsigned short* __restrict__ out, int nnodes)
{
    const int wid = threadIdx.x >> 6, lane = threadIdx.x & 63;
    const int node = blockIdx.x * 4 + wid;
    if (node >= nnodes) return;
    const int g = lane >> 4;            // 0..3
    const int f16 = (lane & 15) * 16;   // feature index (and byte offset)
    const unsigned char* supf = sup + f16;
    const int beg = rp[node], end = rp[node + 1];

    f32x2 a2[8];
#pragma unroll
    for (int i = 0; i < 8; i++) a2[i] = (f32x2){0.f, 0.f};

    int e = beg;
    const int nmain = (end - beg) >> 3;     // 8-edge chunks (wave-uniform)
    if (nmain > 0) {
        unsigned int cp0 = ep[e + g], cp1 = ep[e + 4 + g];
        uint4 cr0 = *(const uint4*)(supf + (size_t)(cp0 & 0x1ffffu) * 256);
        uint4 cr1 = *(const uint4*)(supf + (size_t)(cp1 & 0x1ffffu) * 256);
        unsigned int np0 = 0, np1 = 0;
        if (nmain > 1) {
            np0 = ep[e + 8 + g]; np1 = ep[e + 12 + g];
        }
        for (int it = 0; it + 1 < nmain; ++it) {
            // issue gathers for chunk it+1 (packed words arrived an iteration ago)
            const uint4 nr0 = *(const uint4*)(supf + (size_t)(np0 & 0x1ffffu) * 256);
            const uint4 nr1 = *(const uint4*)(supf + (size_t)(np1 & 0x1ffffu) * 256);
            // issue packed edge loads for chunk it+2
            unsigned int mp0 = 0, mp1 = 0;
            if (it + 2 < nmain) {
                const int eb = e + (it + 2) * 8;
                mp0 = ep[eb + g]; mp1 = ep[eb + 4 + g];
            }
            // decode chunk it (waits only on cr0/cr1; nr + mp stay in flight)
            const float w0 = unpackw(cp0), w1 = unpackw(cp1);
            acc16f8_pk(a2, cr0, (f32x2){w0, w0});
            acc16f8_pk(a2, cr1, (f32x2){w1, w1});
            cr0 = nr0; cr1 = nr1; cp0 = np0; cp1 = np1;
            np0 = mp0; np1 = mp1;
        }
        const float w0 = unpackw(cp0), w1 = unpackw(cp1);
        acc16f8_pk(a2, cr0, (f32x2){w0, w0});
        acc16f8_pk(a2, cr1, (f32x2){w1, w1});
        e += nmain * 8;
    }
    for (; e + 4 <= end; e += 4) {
        const unsigned int p = ep[e + g];
        const uint4 r = *(const uint4*)(supf + (size_t)(p & 0x1ffffu) * 256);
        const float w = unpackw(p);
        acc16f8_pk(a2, r, (f32x2){w, w});
    }
    {
        const int rem = end - e;         // 0..3
        if (g < rem) {
            const unsigned int p = ep[e + g];
            const uint4 r = *(const uint4*)(supf + (size_t)(p & 0x1ffffu) * 256);
            const float w = unpackw(p);
            acc16f8_pk(a2, r, (f32x2){w, w});
        }
    }

    float a[16];
#pragma unroll
    for (int i = 0; i < 8; i++) { a[2 * i] = a2[i].x; a[2 * i + 1] = a2[i].y; }
#pragma unroll
    for (int i = 0; i < 16; i++) {
        a[i] += __shfl_xor(a[i], 16);
        a[i] += __shfl_xor(a[i], 32);
    }

    if (g == 0) {
        const float4 b0 = *(const float4*)(bias + f16);
        const float4 b1 = *(const float4*)(bias + f16 + 4);
        const float4 b2 = *(const float4*)(bias + f16 + 8);
        const float4 b3 = *(const float4*)(bias + f16 + 12);
        a[0] += b0.x; a[1] += b0.y; a[2]  += b0.z; a[3]  += b0.w;
        a[4] += b1.x; a[5] += b1.y; a[6]  += b1.z; a[7]  += b1.w;
        a[8] += b2.x; a[9] += b2.y; a[10] += b2.z; a[11] += b2.w;
        a[12] += b3.x; a[13] += b3.y; a[14] += b3.z; a[15] += b3.w;
#pragma unroll
        for (int i = 0; i < 16; i++) a[i] = a[i] > 0.f ? a[i] : 0.f;
        uint4 o0, o1;
        o0.x = (unsigned int)f2bf(a[0])  | ((unsigned int)f2bf(a[1])  << 16);
        o0.y = (unsigned int)f2bf(a[2])  | ((unsigned int)f2bf(a[3])  << 16);
        o0.z = (unsigned int)f2bf(a[4])  | ((unsigned int)f2bf(a[5])  << 16);
        o0.w = (unsigned int)f2bf(a[6])  | ((unsigned int)f2bf(a[7])  << 16);
        o1.x = (unsigned int)f2bf(a[8])  | ((unsigned int)f2bf(a[9])  << 16);
        o1.y = (unsigned int)f2bf(a[10]) | ((unsigned int)f2bf(a[11]) << 16);
        o1.z = (unsigned int)f2bf(a[12]) | ((unsigned int)f2bf(a[13]) << 16);
        o1.w = (unsigned int)f2bf(a[14]) | ((unsigned int)f2bf(a[15]) << 16);
        *(uint4*)(out + (size_t)node * 256 + f16) = o0;
        *(uint4*)(out + (size_t)node * 256 + f16 + 8) = o1;
    }
}

// fallback spmm (raw esrc/ew) if the packed-edge array doesn't fit the workspace.
__global__ __launch_bounds__(256) void spmm_fp8_raw_kernel(
    const unsigned char* __restrict__ sup, const int* __restrict__ rp,
    const int* __restrict__ esrc, const float* __restrict__ ew,
    const float* __restrict__ bias, unsigned short* __restrict__ out, int nnodes)
{
    const int wid = threadIdx.x >> 6, lane = threadIdx.x & 63;
    const int node = blockIdx.x * 4 + wid;
    if (node >= nnodes) return;
    const int g = lane >> 4;
    const int f16 = (lane & 15) * 16;
    const unsigned char* supf = sup + f16;
    const int beg = rp[node], end = rp[node + 1];

    f32x2 a2[8];
#pragma unroll
    for (int i = 0; i < 8; i++) a2[i] = (f32x2){0.f, 0.f};

    int e = beg;
    for (; e + 8 <= end; e += 8) {
        const int s0 = esrc[e + g],     s1 = esrc[e + 4 + g];
        const float w0 = ew[e + g],     w1 = ew[e + 4 + g];
        const uint4 r0 = *(const uint4*)(supf + (size_t)s0 * 256);
        const uint4 r1 = *(const uint4*)(supf + (size_t)s1 * 256);
        acc16f8_pk(a2, r0, (f32x2){w0, w0});
        acc16f8_pk(a2, r1, (f32x2){w1, w1});
    }
    for (; e + 4 <= end; e += 4) {
        const int s = esrc[e + g];
        const float w = ew[e + g];
        const uint4 r = *(const uint4*)(supf + (size_t)s * 256);
        acc16f8_pk(a2, r, (f32x2){w, w});
    }
    {
        const int rem = end - e;
        if (g < rem) {
            const int s = esrc[e + g];
            const float w = ew[e + g];
            const uint4 r = *(const uint4*)(supf + (size_t)s * 256);
            acc16f8_pk(a2, r, (f32x2){w, w});
        }
    }
    float a[16];
#pragma unroll
    for (int i = 0; i < 8; i++) { a[2 * i] = a2[i].x; a[2 * i + 1] = a2[i].y; }
#pragma unroll
    for (int i = 0; i < 16; i++) {
        a[i] += __shfl_xor(a[i], 16);
        a[i] += __shfl_xor(a[i], 32);
    }

    if (g == 0) {
        const float4 b0 = *(const float4*)(bias + f16);
        const float4 b1 = *(const float4*)(bias + f16 + 4);
        const float4 b2 = *(const float4*)(bias + f16 + 8);
        const float4 b3 = *(const float4*)(bias + f16 + 12);
        a[0] += b0.x; a[1] += b0.y; a[2]  += b0.z; a[3]  += b0.w;
        a[4] += b1.x; a[5] += b1.y; a[6]  += b1.z; a[7]  += b1.w;
        a[8] += b2.x; a[9] += b2.y; a[10] += b2.z; a[11] += b2.w;
        a[12] += b3.x; a[13] += b3.y; a[14] += b3.z; a[15] += b3.w;
#pragma unroll
        for (int i = 0; i < 16; i++) a[i] = a[i] > 0.f ? a[i] : 0.f;
        uint4 o0, o1;
        o0.x = (unsigned int)f2bf(a[0])  | ((unsigned int)f2bf(a[1])  << 16);
        o0.y = (unsigned int)f2bf(a[2])  | ((unsigned int)f2bf(a[3])  << 16);
        o0.z = (unsigned int)f2bf(a[4])  | ((unsigned int)f2bf(a[5])  << 16);
        o0.w = (unsigned int)f2bf(a[6])  | ((unsigned int)f2bf(a[7])  << 16);
        o1.x = (unsigned int)f2bf(a[8])  | ((unsigned int)f2bf(a[9])  << 16);
        o1.y = (unsigned int)f2bf(a[10]) | ((unsigned int)f2bf(a[11]) << 16);
        o1.z = (unsigned int)f2bf(a[12]) | ((unsigned int)f2bf(a[13]) << 16);
        o1.w = (unsigned int)f2bf(a[14]) | ((unsigned int)f2bf(a[15]) << 16);
        *(uint4*)(out + (size_t)node * 256 + f16) = o0;
        *(uint4*)(out + (size_t)node * 256 + f16 + 8) = o1;
    }
}

extern "C" void kernel_launch(void* const* d_in, const int* in_sizes, int n_in,
                              void* d_out, int out_size, void* d_ws, size_t ws_size,
                              hipStream_t stream) {
    const float* x    = (const float*)d_in[0];
    const int*   esrc = (const int*)d_in[1];
    const int*   edst = (const int*)d_in[2];
    const float* ew   = (const float*)d_in[3];
    const float* W1   = (const float*)d_in[4];
    const float* b1   = (const float*)d_in[5];
    const float* W2   = (const float*)d_in[6];
    const float* b2   = (const float*)d_in[7];
    const float* WL1  = (const float*)d_in[8];
    const float* bL1  = (const float*)d_in[9];
    const float* WL2  = (const float*)d_in[10];
    const float* bL2  = (const float*)d_in[11];
    float* out = (float*)d_out;

    const int N = in_sizes[0] / 256;   // 100000
    const int E = in_sizes[1];         // 3200000

    char* ws = (char*)d_ws;
    size_t off = 0;
    auto alloc = [&](size_t bytes) -> void* {
        void* p = ws + off;
        off = (off + bytes + 511) & ~(size_t)511;   // 512B-align: rows stay line-aligned
        return p;
    };
    int* rp              = (int*)alloc((size_t)(N + 1) * 4);
    unsigned short* W1t  = (unsigned short*)alloc((size_t)256 * 256 * 2);
    unsigned short* W2t  = (unsigned short*)alloc((size_t)256 * 256 * 2);
    unsigned short* WLt  = (unsigned short*)alloc((size_t)128 * 256 * 2);
    float* b1p           = (float*)alloc(256 * 4);
    float* b2p           = (float*)alloc(256 * 4);
    unsigned char* sup8  = (unsigned char*)alloc((size_t)N * 256);      // fp8 support (both layers)
    unsigned short* hbuf = (unsigned short*)alloc((size_t)N * 256 * 2); // h1/h2
    unsigned int* ep     = (unsigned int*)alloc((size_t)E * 4);         // packed edges (LAST alloc)
    const bool packed = (off <= ws_size);   // ws overflow guard: fall back to raw esrc/ew

    const int mblocks = (N + 127) / 128;

    rowptr_kernel<<<(E + 255) / 256, 256, 0, stream>>>(edst, rp, E, N);
    if (packed)
        epack_kernel<<<(E / 4 + 255) / 256, 256, 0, stream>>>(esrc, ew, ep, E / 4);
    prep_kernel<<<642, 256, 0, stream>>>(W1, W2, WL1, WL2, b1, b2, W1t, W2t, WLt, b1p, b2p);

    // layer 1: fused fp32->bf16 A staging (x2bf eliminated); support fp8 (sg-permuted cols)
    gemm_f8_x32_kernel<<<dim3(2, mblocks), 256, 0, stream>>>(x, W1t, sup8, N);
    if (packed)
        spmm_fp8_kernel<<<(N + 3) / 4, 256, 0, stream>>>(sup8, rp, ep, b1p, hbuf, N);
    else
        spmm_fp8_raw_kernel<<<(N + 3) / 4, 256, 0, stream>>>(sup8, rp, esrc, ew, b1p, hbuf, N);
    // layer 2 (W2t k-rows pre-permuted to consume sg order; output sg-permuted again)
    gemm_f8_kernel<<<dim3(2, mblocks), 256, 0, stream>>>(hbuf, W2t, sup8, N);
    if (packed)
        spmm_fp8_kernel<<<(N + 3) / 4, 256, 0, stream>>>(sup8, rp, ep, b2p, hbuf, N);
    else
        spmm_fp8_raw_kernel<<<(N + 3) / 4, 256, 0, stream>>>(sup8, rp, esrc, ew, b2p, hbuf, N);
    head_kernel<<<mblocks, 256, 0, stream>>>(hbuf, WLt, bL1, bL2, out, N);
}